// Round 1
// baseline (2813.006 us; speedup 1.0000x reference)
//
#include <hip/hip_runtime.h>
#include <math.h>

#define SS 512
#define HH 768
#define NEGV -1e9f

__device__ __forceinline__ float telu_f(float x){ return x * tanhf(expf(x)); }

__device__ __forceinline__ float wred_max(float v){
  #pragma unroll
  for (int o=32;o>0;o>>=1) v = fmaxf(v, __shfl_xor(v, o));
  return v;
}
__device__ __forceinline__ float wred_sum(float v){
  #pragma unroll
  for (int o=32;o>0;o>>=1) v += __shfl_xor(v, o);
  return v;
}

// K0: per-batch SEP scan + mask counts
__global__ __launch_bounds__(512) void k_scan(const int* __restrict__ ids, const int* __restrict__ am,
                       int* s1a, int* s2a, float* invnam, float* invnp, float* invnh){
  int b = blockIdx.x, tid = threadIdx.x;
  __shared__ int mn, mx, cnt;
  if (tid==0){ mn = 1<<30; mx = -1; cnt = 0; }
  __syncthreads();
  int id = ids[b*SS+tid];
  if (id==102){ atomicMin(&mn, tid); atomicMax(&mx, tid); }
  atomicAdd(&cnt, am[b*SS+tid]);
  __syncthreads();
  if (tid==0){
    int s1 = mn; if (s1 > 255) s1 = 255; if (s1 < 1) s1 = 1;
    int s2 = mx; if (s2 < s1+1) s2 = s1+1; if (s2 > 511) s2 = 511;
    s1a[b]=s1; s2a[b]=s2;
    invnam[b] = 1.f/fmaxf((float)cnt, 1e-9f);
    invnp[b]  = 1.f/fmaxf((float)(s1-1), 1e-9f);
    invnh[b]  = 1.f/fmaxf((float)(s2-s1-1), 1e-9f);
  }
}

// K1: pooled + masked mean + masked max + prem/hyp means -> xfe, sdiff
__global__ __launch_bounds__(256) void k_reps(const float* __restrict__ hs, const int* __restrict__ amask,
     const int* __restrict__ s1a, const int* __restrict__ s2a,
     const float* __restrict__ invnam, const float* __restrict__ invnp, const float* __restrict__ invnh,
     float* __restrict__ xfe, float* __restrict__ sdiff){
  int b = blockIdx.x;
  int h = blockIdx.y*256 + threadIdx.x;
  __shared__ int ams[SS];
  for (int s=threadIdx.x; s<SS; s+=256) ams[s] = amask[b*SS+s];
  __syncthreads();
  int s1 = s1a[b], s2 = s2a[b];
  float sm=0.f, mx=NEGV, sp=0.f, sh=0.f;
  for (int s=0;s<SS;s++){
    float x = hs[((size_t)(b*SS+s))*HH + h];
    if (ams[s] > 0){ sm += x; mx = fmaxf(mx, x); }
    if (s>=1 && s<s1) sp += x;
    if (s>s1 && s<s2) sh += x;
  }
  float pooled = hs[((size_t)(b*SS))*HH + h];
  xfe[b*HH+h]   = pooled + sm*invnam[b] + mx;
  sdiff[b*HH+h] = fabsf(sp*invnp[b] - sh*invnh[b]);
}

// K2: feature branch (768->512 FC + LN + 512->128 FC + telu)
__global__ __launch_bounds__(512) void k_feat(const float* __restrict__ xfe,
    const float* __restrict__ w1, const float* __restrict__ b1,
    const float* __restrict__ g, const float* __restrict__ be,
    const float* __restrict__ w2, const float* __restrict__ b2,
    float* __restrict__ comb){
  int b = blockIdx.x, tid = threadIdx.x;
  __shared__ float x[HH];
  __shared__ float hn[512];
  __shared__ float red[512];
  for (int i=tid;i<HH;i+=512) x[i] = xfe[b*HH+i];
  __syncthreads();
  float hv = b1[tid];
  for (int k=0;k<HH;k++) hv += x[k]*w1[(size_t)k*512 + tid];
  red[tid] = hv; __syncthreads();
  for (int st=256;st>0;st>>=1){ if (tid<st) red[tid]+=red[tid+st]; __syncthreads(); }
  float mean = red[0]*(1.f/512.f);
  __syncthreads();
  float dv = hv-mean; red[tid]=dv*dv; __syncthreads();
  for (int st=256;st>0;st>>=1){ if (tid<st) red[tid]+=red[tid+st]; __syncthreads(); }
  float var = red[0]*(1.f/512.f);
  __syncthreads();
  hn[tid] = dv * (1.f/sqrtf(var + 1e-5f)) * g[tid] + be[tid];
  __syncthreads();
  if (tid < 128){
    float f = b2[tid];
    for (int k=0;k<512;k++) f += hn[k]*w2[k*128+tid];
    comb[b*512+tid] = telu_f(f);
  }
}

// K3: diff branch
__global__ __launch_bounds__(128) void k_diff(const float* __restrict__ sdiff,
    const float* __restrict__ w, const float* __restrict__ bb, float* __restrict__ comb){
  int b=blockIdx.x, tid=threadIdx.x;
  __shared__ float sd[HH];
  for (int i=tid;i<HH;i+=128) sd[i]=sdiff[b*HH+i];
  __syncthreads();
  float f = bb[tid];
  for (int k=0;k<HH;k++) f += sd[k]*w[(size_t)k*128+tid];
  comb[b*512+128+tid] = telu_f(f);
}

// K4: QKV projection GEMM. q all rows; k/v only rows s<256 (prem keys < s1 <= 255).
__global__ __launch_bounds__(256) void k_qkv(const float* __restrict__ hs,
    const float* __restrict__ wq, const float* __restrict__ wk, const float* __restrict__ wv,
    const float* __restrict__ bq, const float* __restrict__ bk, const float* __restrict__ bv,
    float* __restrict__ qb, float* __restrict__ kb, float* __restrict__ vb){
  int rt = blockIdx.x, ct = blockIdx.y;
  int cbase = ct*64;
  int which = cbase/HH;
  int n0 = cbase - which*HH;
  int r0 = rt*64;
  int s0 = r0 & (SS-1);
  int b  = r0 >> 9;
  if (which>0 && s0>=256) return;
  const float* Wm   = which==0? wq : (which==1? wk : wv);
  const float* bias = which==0? bq : (which==1? bk : bv);
  __shared__ float As[16][64];
  __shared__ float Bs[16][64];
  int tid=threadIdx.x;
  int arow = tid>>2, akoff = (tid&3)*4;
  int brow = tid>>4, bcoff = (tid&15)*4;
  const float* Ap = hs + (size_t)(r0+arow)*HH + akoff;
  const float* Wp = Wm + (size_t)brow*HH + n0 + bcoff;
  int ty=tid>>4, tx=tid&15;
  float c[4][4]={};
  for (int k0=0;k0<HH;k0+=16){
    float4 a4 = *(const float4*)(Ap + k0);
    float4 b4 = *(const float4*)(Wp + (size_t)k0*HH);
    As[akoff+0][arow]=a4.x; As[akoff+1][arow]=a4.y; As[akoff+2][arow]=a4.z; As[akoff+3][arow]=a4.w;
    *(float4*)&Bs[brow][bcoff] = b4;
    __syncthreads();
    #pragma unroll
    for (int kk=0;kk<16;kk++){
      float4 av  = *(const float4*)&As[kk][ty*4];
      float4 bv4 = *(const float4*)&Bs[kk][tx*4];
      float aa[4]={av.x,av.y,av.z,av.w};
      float bb[4]={bv4.x,bv4.y,bv4.z,bv4.w};
      #pragma unroll
      for (int i=0;i<4;i++){
        #pragma unroll
        for (int j=0;j<4;j++) c[i][j] += aa[i]*bb[j];
      }
    }
    __syncthreads();
  }
  float4 bias4 = *(const float4*)(bias + n0 + tx*4);
  float bb4[4] = {bias4.x,bias4.y,bias4.z,bias4.w};
  #pragma unroll
  for (int i=0;i<4;i++){
    int r = r0 + ty*4 + i;
    int s = r & (SS-1);
    float4 o; o.x=c[i][0]+bb4[0]; o.y=c[i][1]+bb4[1]; o.z=c[i][2]+bb4[2]; o.w=c[i][3]+bb4[3];
    int n = n0 + tx*4;
    if (which==0)      *(float4*)(qb + (size_t)r*HH + n) = o;
    else if (which==1) *(float4*)(kb + ((size_t)(b*256+s))*HH + n) = o;
    else               *(float4*)(vb + ((size_t)(b*256+s))*HH + n) = o;
  }
}

// K5: attention — per (b,head). For q in hyp range, softmax over prem keys, accumulate u[k].
__global__ __launch_bounds__(256) void k_attn(const float* __restrict__ qb, const float* __restrict__ kb,
    const int* __restrict__ s1a, const int* __restrict__ s2a, float* __restrict__ uws){
  int bh = blockIdx.x;
  int b = bh>>3, h = bh&7;
  int s1 = s1a[b], s2 = s2a[b];
  int tid=threadIdx.x, wave=tid>>6, lane=tid&63;
  __shared__ float qv[4][96];
  __shared__ float usum[4][256];
  float ureg[4]={0.f,0.f,0.f,0.f};
  const float scale = 0.1020620726f;   // 1/sqrt(96)
  for (int q0 = s1+1; q0 < s2; q0 += 4){
    for (int t=tid; t<384; t+=256){
      int w=t/96, d=t-w*96;
      int q=q0+w;
      qv[w][d] = (q<s2) ? qb[((size_t)(b*SS+q))*HH + h*96 + d] : 0.f;
    }
    __syncthreads();
    int q = q0+wave;
    if (q < s2){
      float sc[4];
      float mx = -1e30f;
      #pragma unroll
      for (int j=0;j<4;j++){
        int k = 1 + lane + 64*j;
        if (k < s1){
          const float4* kp = (const float4*)(kb + ((size_t)(b*256+k))*HH + h*96);
          const float4* qp = (const float4*)(&qv[wave][0]);
          float acc = 0.f;
          #pragma unroll
          for (int cc=0;cc<24;cc++){
            float4 kk = kp[cc]; float4 qq = qp[cc];
            acc += kk.x*qq.x + kk.y*qq.y + kk.z*qq.z + kk.w*qq.w;
          }
          sc[j] = acc*scale;
        } else sc[j] = -1e30f;
        mx = fmaxf(mx, sc[j]);
      }
      mx = wred_max(mx);
      float p[4]; float ls = 0.f;
      #pragma unroll
      for (int j=0;j<4;j++){
        int k = 1+lane+64*j;
        p[j] = (k<s1) ? expf(sc[j]-mx) : 0.f;
        ls += p[j];
      }
      ls = wred_sum(ls);
      float inv = 1.f/ls;
      #pragma unroll
      for (int j=0;j<4;j++) ureg[j] += p[j]*inv;
    }
    __syncthreads();
  }
  #pragma unroll
  for (int j=0;j<4;j++) usum[wave][lane+64*j] = ureg[j];
  __syncthreads();
  uws[(size_t)bh*256 + tid] = usum[0][tid]+usum[1][tid]+usum[2][tid]+usum[3][tid];
}

// K6: finish attn_rep: cm = u@v / nh ; acc = cm@wo + bo ; telu(acc@apw + apb)
__global__ __launch_bounds__(256) void k_attnrep(const float* __restrict__ uws, const float* __restrict__ vb,
    const float* __restrict__ wo, const float* __restrict__ bo,
    const float* __restrict__ apw, const float* __restrict__ apb,
    const int* __restrict__ s1a, const float* __restrict__ invnh, float* __restrict__ comb){
  int b=blockIdx.x, tid=threadIdx.x;
  int s1=s1a[b]; int nk=s1-1;
  float inh = invnh[b];
  __shared__ float cm[HH];
  __shared__ float acc[HH];
  for (int i=tid;i<HH;i+=256){
    int h=i/96;
    const float* up = uws + (size_t)(b*8+h)*256;
    float a=0.f;
    for (int sl=0; sl<nk; sl++) a += up[sl]*vb[((size_t)(b*256+sl+1))*HH + i];
    cm[i]=a*inh;
  }
  __syncthreads();
  for (int j=tid;j<HH;j+=256){
    float a = bo[j];
    for (int i=0;i<HH;i++) a += cm[i]*wo[(size_t)i*HH+j];
    acc[j]=a;
  }
  __syncthreads();
  if (tid<128){
    float a = apb[tid];
    for (int i=0;i<HH;i++) a += acc[i]*apw[(size_t)i*128+tid];
    comb[b*512+256+tid]=telu_f(a);
  }
}

// K7: sim = hs @ hs^T, tiles 32x64, skip tiles beyond s2
__global__ __launch_bounds__(256) void k_sim(const float* __restrict__ hs, const int* __restrict__ s2a,
                                             float* __restrict__ sim){
  int b = blockIdx.z;
  int s0 = blockIdx.x*32, t0 = blockIdx.y*64;
  int s2 = s2a[b];
  if (s0 >= s2 || t0 >= s2) return;
  __shared__ float As[16][32];
  __shared__ float Bs[16][64];
  int tid=threadIdx.x;
  float c[2][4] = {};
  int ty = tid>>4, tx = tid&15;
  const float* base = hs + (size_t)b*SS*HH;
  for (int k0=0;k0<HH;k0+=16){
    if (tid < 128){
      int row = tid>>2, koff=(tid&3)*4;
      float4 a4 = *(const float4*)(base + (size_t)(s0+row)*HH + k0+koff);
      As[koff+0][row]=a4.x; As[koff+1][row]=a4.y; As[koff+2][row]=a4.z; As[koff+3][row]=a4.w;
    }
    {
      int row = tid>>2, koff=(tid&3)*4;
      float4 b4 = *(const float4*)(base + (size_t)(t0+row)*HH + k0+koff);
      Bs[koff+0][row]=b4.x; Bs[koff+1][row]=b4.y; Bs[koff+2][row]=b4.z; Bs[koff+3][row]=b4.w;
    }
    __syncthreads();
    #pragma unroll
    for (int kk=0;kk<16;kk++){
      float a0 = As[kk][ty*2], a1 = As[kk][ty*2+1];
      float4 b4 = *(const float4*)&Bs[kk][tx*4];
      c[0][0]+=a0*b4.x; c[0][1]+=a0*b4.y; c[0][2]+=a0*b4.z; c[0][3]+=a0*b4.w;
      c[1][0]+=a1*b4.x; c[1][1]+=a1*b4.y; c[1][2]+=a1*b4.z; c[1][3]+=a1*b4.w;
    }
    __syncthreads();
  }
  #pragma unroll
  for (int i=0;i<2;i++){
    int s = s0 + ty*2 + i;
    float4 o; o.x=c[i][0]; o.y=c[i][1]; o.z=c[i][2]; o.w=c[i][3];
    *(float4*)(sim + ((size_t)(b*SS+s))*SS + t0 + tx*4) = o;
  }
}

// K8: masked row-softmax of sim, column-sum into v1 (prem rows / hyp cols) and v2 (hyp rows / prem cols)
__global__ __launch_bounds__(256) void k_simsm(const float* __restrict__ sim,
    const int* __restrict__ s1a, const int* __restrict__ s2a,
    float* __restrict__ v1g, float* __restrict__ v2g){
  int b = blockIdx.x;
  int s1 = s1a[b], s2 = s2a[b];
  int tid=threadIdx.x, wave=tid>>6, lane=tid&63;
  __shared__ float av[2][4][SS];   // 16 KB
  for (int i=tid;i<2*4*SS;i+=256) ((float*)av)[i]=0.f;
  __syncthreads();
  for (int r = wave; r < SS; r += 4){
    int t0,t1,which;
    if (r>=1 && r<s1){ t0=s1+1; t1=s2; which=0; }
    else if (r>s1 && r<s2){ t0=1; t1=s1; which=1; }
    else continue;
    const float* row = sim + ((size_t)(b*SS+r))*SS;
    float vals[7]; float mx=-1e30f;
    #pragma unroll
    for (int j=0;j<7;j++){
      int t = t0 + lane + 64*j;
      vals[j] = (t<t1) ? row[t] : -1e30f;
      mx = fmaxf(mx, vals[j]);
    }
    mx = wred_max(mx);
    float ssum=0.f;
    #pragma unroll
    for (int j=0;j<7;j++){
      int t = t0+lane+64*j;
      vals[j] = (t<t1)? expf(vals[j]-mx) : 0.f;
      ssum += vals[j];
    }
    ssum = wred_sum(ssum);
    float inv = 1.f/ssum;
    #pragma unroll
    for (int j=0;j<7;j++){
      int t = t0+lane+64*j;
      if (t<t1) av[which][wave][t] += vals[j]*inv;
    }
  }
  __syncthreads();
  for (int t=tid;t<SS;t+=256){
    v1g[b*SS+t] = av[0][0][t]+av[0][1][t]+av[0][2][t]+av[0][3][t];
    v2g[b*SS+t] = av[1][0][t]+av[1][1][t]+av[1][2][t]+av[1][3][t];
  }
}

// K9: al1 = v1@hs/np, al2 = v2@hs/nh ; tmp = cat@al_w1+b1 ; telu(tmp@al_w2+b2)
__global__ __launch_bounds__(256) void k_align(const float* __restrict__ hs,
    const float* __restrict__ v1g, const float* __restrict__ v2g,
    const float* __restrict__ w1, const float* __restrict__ b1,
    const float* __restrict__ w2, const float* __restrict__ b2,
    const float* __restrict__ invnp, const float* __restrict__ invnh, float* __restrict__ comb){
  int b=blockIdx.x, tid=threadIdx.x;
  __shared__ float sv1[SS], sv2[SS];
  __shared__ float cat[2*HH];
  __shared__ float tmp[HH];
  for (int t=tid;t<SS;t+=256){ sv1[t]=v1g[b*SS+t]; sv2[t]=v2g[b*SS+t]; }
  __syncthreads();
  float inp=invnp[b], inh=invnh[b];
  for (int d=tid; d<HH; d+=256){
    float a1=0.f,a2=0.f;
    for (int t=0;t<SS;t++){
      float x = hs[((size_t)(b*SS+t))*HH + d];
      a1 += sv1[t]*x; a2 += sv2[t]*x;
    }
    cat[d]=a1*inp; cat[HH+d]=a2*inh;
  }
  __syncthreads();
  for (int j=tid;j<HH;j+=256){
    float a=b1[j];
    for (int i=0;i<2*HH;i++) a += cat[i]*w1[(size_t)i*HH+j];
    tmp[j]=a;
  }
  __syncthreads();
  if (tid<128){
    float a=b2[tid];
    for (int i=0;i<HH;i++) a += tmp[i]*w2[i*128+tid];
    comb[b*512+384+tid]=telu_f(a);
  }
}

// K10: classifier head
__global__ __launch_bounds__(64) void k_cls(const float* __restrict__ comb,
    const float* __restrict__ w1, const float* __restrict__ b1,
    const float* __restrict__ w2, const float* __restrict__ b2, float* __restrict__ out){
  int b=blockIdx.x, tid=threadIdx.x;
  __shared__ float cb[512];
  __shared__ float t1[64];
  for (int i=tid;i<512;i+=64) cb[i]=comb[b*512+i];
  __syncthreads();
  float a = b1[tid];
  for (int k=0;k<512;k++) a += cb[k]*w1[(size_t)k*64+tid];
  t1[tid]=telu_f(a);
  __syncthreads();
  if (tid<3){
    float o = b2[tid];
    for (int k=0;k<64;k++) o += t1[k]*w2[k*3+tid];
    out[b*3+tid]=o;
  }
}

extern "C" void kernel_launch(void* const* d_in, const int* in_sizes, int n_in,
                              void* d_out, int out_size, void* d_ws, size_t ws_size,
                              hipStream_t stream){
  const float* hs   = (const float*)d_in[0];
  const int*   ids  = (const int*)d_in[1];
  const int*   amask= (const int*)d_in[2];
  const float* fe_w1= (const float*)d_in[3];
  const float* fe_b1= (const float*)d_in[4];
  const float* fe_g = (const float*)d_in[5];
  const float* fe_be= (const float*)d_in[6];
  const float* fe_w2= (const float*)d_in[7];
  const float* fe_b2= (const float*)d_in[8];
  const float* al_w1= (const float*)d_in[9];
  const float* al_b1= (const float*)d_in[10];
  const float* al_w2= (const float*)d_in[11];
  const float* al_b2= (const float*)d_in[12];
  const float* wq   = (const float*)d_in[13];
  const float* bq   = (const float*)d_in[14];
  const float* wk   = (const float*)d_in[15];
  const float* bk   = (const float*)d_in[16];
  const float* wv   = (const float*)d_in[17];
  const float* bv   = (const float*)d_in[18];
  const float* wo   = (const float*)d_in[19];
  const float* bo   = (const float*)d_in[20];
  const float* dpw  = (const float*)d_in[21];
  const float* dpb  = (const float*)d_in[22];
  const float* apw  = (const float*)d_in[23];
  const float* apb  = (const float*)d_in[24];
  const float* clw1 = (const float*)d_in[25];
  const float* clb1 = (const float*)d_in[26];
  const float* clw2 = (const float*)d_in[27];
  const float* clb2 = (const float*)d_in[28];
  float* out = (float*)d_out;

  float* Wf = (float*)d_ws;
  int* s1a = (int*)d_ws;
  int* s2a = s1a + 32;
  float* invnam = Wf + 64;
  float* invnp  = Wf + 96;
  float* invnh  = Wf + 128;
  float* qb   = Wf + 256;                          // 32*512*768
  float* kb   = qb   + (size_t)32*512*768;         // 32*256*768
  float* vb   = kb   + (size_t)32*256*768;         // 32*256*768
  float* simb = vb   + (size_t)32*256*768;         // 32*512*512
  float* uws  = simb + (size_t)32*512*512;         // 32*8*256
  float* v1g  = uws  + (size_t)32*8*256;           // 32*512
  float* v2g  = v1g  + (size_t)32*512;             // 32*512
  float* xfe  = v2g  + (size_t)32*512;             // 32*768
  float* sdiff= xfe  + (size_t)32*768;             // 32*768
  float* comb = sdiff+ (size_t)32*768;             // 32*512

  k_scan<<<dim3(32), dim3(512), 0, stream>>>(ids, amask, s1a, s2a, invnam, invnp, invnh);
  k_reps<<<dim3(32,3), dim3(256), 0, stream>>>(hs, amask, s1a, s2a, invnam, invnp, invnh, xfe, sdiff);
  k_feat<<<dim3(32), dim3(512), 0, stream>>>(xfe, fe_w1, fe_b1, fe_g, fe_be, fe_w2, fe_b2, comb);
  k_diff<<<dim3(32), dim3(128), 0, stream>>>(sdiff, dpw, dpb, comb);
  k_qkv<<<dim3(256,36), dim3(256), 0, stream>>>(hs, wq, wk, wv, bq, bk, bv, qb, kb, vb);
  k_attn<<<dim3(256), dim3(256), 0, stream>>>(qb, kb, s1a, s2a, uws);
  k_attnrep<<<dim3(32), dim3(256), 0, stream>>>(uws, vb, wo, bo, apw, apb, s1a, invnh, comb);
  k_sim<<<dim3(16,8,32), dim3(256), 0, stream>>>(hs, s2a, simb);
  k_simsm<<<dim3(32), dim3(256), 0, stream>>>(simb, s1a, s2a, v1g, v2g);
  k_align<<<dim3(32), dim3(256), 0, stream>>>(hs, v1g, v2g, al_w1, al_b1, al_w2, al_b2, invnp, invnh, comb);
  k_cls<<<dim3(32), dim3(64), 0, stream>>>(comb, clw1, clb1, clw2, clb2, out);
}

// Round 2
// 1770.916 us; speedup vs baseline: 1.5884x; 1.5884x over previous
//
#include <hip/hip_runtime.h>
#include <hip/hip_bf16.h>
#include <math.h>

#define SS 512
#define HH 768
#define NEGV -1e9f

typedef float f32x4 __attribute__((ext_vector_type(4)));
typedef __bf16 bf16x8 __attribute__((ext_vector_type(8)));

__device__ __forceinline__ float telu_f(float x){ return x * tanhf(expf(x)); }

__device__ __forceinline__ short f2bf(float x){
  __hip_bfloat16 h = __float2bfloat16(x);
  return __builtin_bit_cast(short, h);
}
__device__ __forceinline__ float b2f(short s){
  __hip_bfloat16 h = __builtin_bit_cast(__hip_bfloat16, s);
  return __bfloat162float(h);
}

__device__ __forceinline__ float wred_max(float v){
  #pragma unroll
  for (int o=32;o>0;o>>=1) v = fmaxf(v, __shfl_xor(v, o));
  return v;
}
__device__ __forceinline__ float wred_sum(float v){
  #pragma unroll
  for (int o=32;o>0;o>>=1) v += __shfl_xor(v, o);
  return v;
}

// K0: per-batch SEP scan + mask counts
__global__ __launch_bounds__(512) void k_scan(const int* __restrict__ ids, const int* __restrict__ am,
                       int* s1a, int* s2a, float* invnam, float* invnp, float* invnh){
  int b = blockIdx.x, tid = threadIdx.x;
  __shared__ int mn, mx, cnt;
  if (tid==0){ mn = 1<<30; mx = -1; cnt = 0; }
  __syncthreads();
  int id = ids[b*SS+tid];
  if (id==102){ atomicMin(&mn, tid); atomicMax(&mx, tid); }
  atomicAdd(&cnt, am[b*SS+tid]);
  __syncthreads();
  if (tid==0){
    int s1 = mn; if (s1 > 255) s1 = 255; if (s1 < 1) s1 = 1;
    int s2 = mx; if (s2 < s1+1) s2 = s1+1; if (s2 > 511) s2 = 511;
    s1a[b]=s1; s2a[b]=s2;
    invnam[b] = 1.f/fmaxf((float)cnt, 1e-9f);
    invnp[b]  = 1.f/fmaxf((float)(s1-1), 1e-9f);
    invnh[b]  = 1.f/fmaxf((float)(s2-s1-1), 1e-9f);
  }
}

// K-cvt: hs -> bf16 hi + bf16 lo residual
__global__ __launch_bounds__(256) void k_cvt(const float* __restrict__ hs, short* __restrict__ hsb, short* __restrict__ hsl){
  size_t i = ((size_t)blockIdx.x*256 + threadIdx.x)*8;
  float4 x0 = *(const float4*)(hs+i);
  float4 x1 = *(const float4*)(hs+i+4);
  float xv[8] = {x0.x,x0.y,x0.z,x0.w,x1.x,x1.y,x1.z,x1.w};
  short h[8], l[8];
  #pragma unroll
  for (int j=0;j<8;j++){
    h[j] = f2bf(xv[j]);
    l[j] = f2bf(xv[j] - b2f(h[j]));
  }
  *(int4*)(hsb+i) = *(const int4*)h;
  *(int4*)(hsl+i) = *(const int4*)l;
}

// K-wt: transpose+convert wq/wk/wv -> Wt[which][n][k] bf16
__global__ __launch_bounds__(256) void k_wt(const float* __restrict__ wq, const float* __restrict__ wk,
                                            const float* __restrict__ wv, short* __restrict__ Wt){
  int k0 = blockIdx.x*32, n0 = blockIdx.y*32, which = blockIdx.z;
  const float* W = which==0? wq : (which==1? wk : wv);
  __shared__ float tl[32][33];
  int t = threadIdx.x;
  int r = t>>3, c4 = (t&7)*4;
  float4 v = *(const float4*)(W + (size_t)(k0+r)*HH + n0 + c4);
  tl[r][c4+0]=v.x; tl[r][c4+1]=v.y; tl[r][c4+2]=v.z; tl[r][c4+3]=v.w;
  __syncthreads();
  short4 o;
  o.x = f2bf(tl[c4+0][r]); o.y = f2bf(tl[c4+1][r]);
  o.z = f2bf(tl[c4+2][r]); o.w = f2bf(tl[c4+3][r]);
  *(short4*)(Wt + (size_t)which*HH*HH + (size_t)(n0+r)*HH + k0 + c4) = o;
}

// K1: pooled + masked mean + masked max + prem/hyp means -> xfe, sdiff  (exact fp32)
__global__ __launch_bounds__(256) void k_reps(const float* __restrict__ hs, const int* __restrict__ amask,
     const int* __restrict__ s1a, const int* __restrict__ s2a,
     const float* __restrict__ invnam, const float* __restrict__ invnp, const float* __restrict__ invnh,
     float* __restrict__ xfe, float* __restrict__ sdiff){
  int b = blockIdx.x;
  int h = blockIdx.y*256 + threadIdx.x;
  __shared__ int ams[SS];
  for (int s=threadIdx.x; s<SS; s+=256) ams[s] = amask[b*SS+s];
  __syncthreads();
  int s1 = s1a[b], s2 = s2a[b];
  float sm=0.f, mx=NEGV, sp=0.f, sh=0.f;
  for (int s=0;s<SS;s++){
    float x = hs[((size_t)(b*SS+s))*HH + h];
    if (ams[s] > 0){ sm += x; mx = fmaxf(mx, x); }
    if (s>=1 && s<s1) sp += x;
    if (s>s1 && s<s2) sh += x;
  }
  float pooled = hs[((size_t)(b*SS))*HH + h];
  xfe[b*HH+h]   = pooled + sm*invnam[b] + mx;
  sdiff[b*HH+h] = fabsf(sp*invnp[b] - sh*invnh[b]);
}

// K2: feature branch
__global__ __launch_bounds__(512) void k_feat(const float* __restrict__ xfe,
    const float* __restrict__ w1, const float* __restrict__ b1,
    const float* __restrict__ g, const float* __restrict__ be,
    const float* __restrict__ w2, const float* __restrict__ b2,
    float* __restrict__ comb){
  int b = blockIdx.x, tid = threadIdx.x;
  __shared__ float x[HH];
  __shared__ float hn[512];
  __shared__ float red[512];
  for (int i=tid;i<HH;i+=512) x[i] = xfe[b*HH+i];
  __syncthreads();
  float hv = b1[tid];
  for (int k=0;k<HH;k++) hv += x[k]*w1[(size_t)k*512 + tid];
  red[tid] = hv; __syncthreads();
  for (int st=256;st>0;st>>=1){ if (tid<st) red[tid]+=red[tid+st]; __syncthreads(); }
  float mean = red[0]*(1.f/512.f);
  __syncthreads();
  float dv = hv-mean; red[tid]=dv*dv; __syncthreads();
  for (int st=256;st>0;st>>=1){ if (tid<st) red[tid]+=red[tid+st]; __syncthreads(); }
  float var = red[0]*(1.f/512.f);
  __syncthreads();
  hn[tid] = dv * (1.f/sqrtf(var + 1e-5f)) * g[tid] + be[tid];
  __syncthreads();
  if (tid < 128){
    float f = b2[tid];
    for (int k=0;k<512;k++) f += hn[k]*w2[k*128+tid];
    comb[b*512+tid] = telu_f(f);
  }
}

// K3: diff branch
__global__ __launch_bounds__(128) void k_diff(const float* __restrict__ sdiff,
    const float* __restrict__ w, const float* __restrict__ bb, float* __restrict__ comb){
  int b=blockIdx.x, tid=threadIdx.x;
  __shared__ float sd[HH];
  for (int i=tid;i<HH;i+=128) sd[i]=sdiff[b*HH+i];
  __syncthreads();
  float f = bb[tid];
  for (int k=0;k<HH;k++) f += sd[k]*w[(size_t)k*128+tid];
  comb[b*512+128+tid] = telu_f(f);
}

// K4: QKV MFMA GEMM, 128x128 tiles, bf16. q stored bf16; k/v fp32 (rows s<256 only).
__global__ __launch_bounds__(256) void k_qkv_mfma(const short* __restrict__ hsb, const short* __restrict__ Wt,
    const float* __restrict__ bq, const float* __restrict__ bk, const float* __restrict__ bv,
    short* __restrict__ qbh, float* __restrict__ kb, float* __restrict__ vb){
  int rt = blockIdx.x;               // 128 row tiles of 128
  int ct = blockIdx.y;               // 18: which = ct/6, n-tile = ct%6
  int which = ct/6;
  int n0 = (ct - which*6)*128;
  int r0 = rt*128;
  int s0 = r0 & (SS-1);
  int b  = r0 >> 9;
  if (which>0 && s0 >= 256) return;
  const float* bias = which==0? bq : (which==1? bk : bv);
  const short* Wb = Wt + (size_t)which*HH*HH;

  __shared__ short As[128][40];
  __shared__ short Bs[128][40];
  int tid = threadIdx.x;
  int wv_ = tid>>6, lane = tid&63;
  int wm = wv_>>1, wn = wv_&1;
  int lm = lane&15, lq = lane>>4;

  int srow = tid>>2;       // 0..63
  int skc  = tid&3;        // 8-elem k chunk

  f32x4 acc[4][4];
  #pragma unroll
  for (int i=0;i<4;i++)
    #pragma unroll
    for (int j=0;j<4;j++) acc[i][j] = (f32x4){0.f,0.f,0.f,0.f};

  for (int k0=0;k0<HH;k0+=32){
    int4 a0 = *(const int4*)(hsb + (size_t)(r0+srow)*HH    + k0 + skc*8);
    int4 a1 = *(const int4*)(hsb + (size_t)(r0+srow+64)*HH + k0 + skc*8);
    int4 b0 = *(const int4*)(Wb  + (size_t)(n0+srow)*HH    + k0 + skc*8);
    int4 b1 = *(const int4*)(Wb  + (size_t)(n0+srow+64)*HH + k0 + skc*8);
    __syncthreads();
    *(int4*)&As[srow][skc*8]    = a0;
    *(int4*)&As[srow+64][skc*8] = a1;
    *(int4*)&Bs[srow][skc*8]    = b0;
    *(int4*)&Bs[srow+64][skc*8] = b1;
    __syncthreads();
    bf16x8 af[4], bfv[4];
    #pragma unroll
    for (int i=0;i<4;i++) af[i]  = *(const bf16x8*)&As[wm*64 + i*16 + lm][lq*8];
    #pragma unroll
    for (int j=0;j<4;j++) bfv[j] = *(const bf16x8*)&Bs[wn*64 + j*16 + lm][lq*8];
    #pragma unroll
    for (int i=0;i<4;i++)
      #pragma unroll
      for (int j=0;j<4;j++)
        acc[i][j] = __builtin_amdgcn_mfma_f32_16x16x32_bf16(af[i], bfv[j], acc[i][j], 0, 0, 0);
  }
  #pragma unroll
  for (int i=0;i<4;i++){
    #pragma unroll
    for (int j=0;j<4;j++){
      int col = n0 + wn*64 + j*16 + lm;
      float bcol = bias[col];
      #pragma unroll
      for (int r4=0;r4<4;r4++){
        int row = r0 + wm*64 + i*16 + lq*4 + r4;
        float val = acc[i][j][r4] + bcol;
        if (which==0)      qbh[(size_t)row*HH + col] = f2bf(val);
        else {
          int s = row & (SS-1);
          size_t o = ((size_t)(b*256+s))*HH + col;
          if (which==1) kb[o] = val; else vb[o] = val;
        }
      }
    }
  }
}

// K5: attention u-weights; grid (b, h, qc) — q-range chunked 8 ways
__global__ __launch_bounds__(256) void k_attn(const short* __restrict__ qbh, const float* __restrict__ kb,
    const int* __restrict__ s1a, const int* __restrict__ s2a, float* __restrict__ upart){
  int b = blockIdx.x, h = blockIdx.y, qc = blockIdx.z;
  int s1 = s1a[b], s2 = s2a[b];
  int L = s2 - s1 - 1;
  int C = (L + 7) >> 3;
  int qs = s1 + 1 + qc*C;
  int qe = qs + C; if (qe > s2) qe = s2;
  int tid=threadIdx.x, wave=tid>>6, lane=tid&63;
  __shared__ float qv[4][96];
  __shared__ float usum[4][256];
  float ureg[4]={0.f,0.f,0.f,0.f};
  const float scale = 0.1020620726f;   // 1/sqrt(96)
  for (int q0 = qs; q0 < qe; q0 += 4){
    for (int t=tid; t<384; t+=256){
      int w=t/96, d=t-w*96;
      int q=q0+w;
      qv[w][d] = (q<qe) ? b2f(qbh[((size_t)(b*SS+q))*HH + h*96 + d]) : 0.f;
    }
    __syncthreads();
    int q = q0+wave;
    if (q < qe){
      float sc[4];
      float mx = -1e30f;
      #pragma unroll
      for (int j=0;j<4;j++){
        int k = 1 + lane + 64*j;
        if (k < s1){
          const float4* kp = (const float4*)(kb + ((size_t)(b*256+k))*HH + h*96);
          const float4* qp = (const float4*)(&qv[wave][0]);
          float acc = 0.f;
          #pragma unroll
          for (int cc=0;cc<24;cc++){
            float4 kk = kp[cc]; float4 qq = qp[cc];
            acc += kk.x*qq.x + kk.y*qq.y + kk.z*qq.z + kk.w*qq.w;
          }
          sc[j] = acc*scale;
        } else sc[j] = -1e30f;
        mx = fmaxf(mx, sc[j]);
      }
      mx = wred_max(mx);
      float p[4]; float ls = 0.f;
      #pragma unroll
      for (int j=0;j<4;j++){
        int k = 1+lane+64*j;
        p[j] = (k<s1) ? expf(sc[j]-mx) : 0.f;
        ls += p[j];
      }
      ls = wred_sum(ls);
      float inv = 1.f/ls;
      #pragma unroll
      for (int j=0;j<4;j++) ureg[j] += p[j]*inv;
    }
    __syncthreads();
  }
  #pragma unroll
  for (int j=0;j<4;j++) usum[wave][lane+64*j] = ureg[j];
  __syncthreads();
  upart[(((size_t)(b*8+h))*8 + qc)*256 + tid] = usum[0][tid]+usum[1][tid]+usum[2][tid]+usum[3][tid];
}

// K6: attn_rep finish
__global__ __launch_bounds__(256) void k_attnrep(const float* __restrict__ upart, const float* __restrict__ vb,
    const float* __restrict__ wo, const float* __restrict__ bo,
    const float* __restrict__ apw, const float* __restrict__ apb,
    const int* __restrict__ s1a, const float* __restrict__ invnh, float* __restrict__ comb){
  int b=blockIdx.x, tid=threadIdx.x;
  int s1=s1a[b]; int nk=s1-1;
  float inh = invnh[b];
  __shared__ float us[8][256];
  __shared__ float cm[HH];
  __shared__ float acc[HH];
  for (int idx=tid; idx<2048; idx+=256){
    int h = idx>>8, sl = idx&255;
    const float* up = upart + (((size_t)(b*8+h))*8)*256;
    float a=0.f;
    #pragma unroll
    for (int qc=0;qc<8;qc++) a += up[qc*256 + sl];
    us[h][sl] = a;
  }
  __syncthreads();
  for (int i=tid;i<HH;i+=256){
    int h=i/96;
    float a=0.f;
    for (int sl=0; sl<nk; sl++) a += us[h][sl+1]*vb[((size_t)(b*256+sl+1))*HH + i];
    cm[i]=a*inh;
  }
  __syncthreads();
  for (int j=tid;j<HH;j+=256){
    float a = bo[j];
    for (int i=0;i<HH;i++) a += cm[i]*wo[(size_t)i*HH+j];
    acc[j]=a;
  }
  __syncthreads();
  if (tid<128){
    float a = apb[tid];
    for (int i=0;i<HH;i++) a += acc[i]*apw[(size_t)i*128+tid];
    comb[b*512+256+tid]=telu_f(a);
  }
}

// K7: sim = hs@hs^T via split-precision bf16 MFMA (hi*hi + hi*lo + lo*hi)
__global__ __launch_bounds__(256) void k_sim_mfma(const short* __restrict__ hsb, const short* __restrict__ hsl,
    const int* __restrict__ s2a, float* __restrict__ sim){
  int b = blockIdx.z;
  int s0 = blockIdx.x*128, t0 = blockIdx.y*128;
  int s2 = s2a[b];
  if (s0 >= s2 || t0 >= s2) return;
  __shared__ short Ah[128][40];
  __shared__ short Al[128][40];
  __shared__ short Bh[128][40];
  __shared__ short Bl[128][40];
  int tid = threadIdx.x;
  int wv_ = tid>>6, lane = tid&63;
  int wm = wv_>>1, wn = wv_&1;
  int lm = lane&15, lq = lane>>4;
  int srow = tid>>2, skc = tid&3;
  const size_t base = (size_t)b*SS*HH;

  f32x4 acc[4][4];
  #pragma unroll
  for (int i=0;i<4;i++)
    #pragma unroll
    for (int j=0;j<4;j++) acc[i][j] = (f32x4){0.f,0.f,0.f,0.f};

  for (int k0=0;k0<HH;k0+=32){
    int4 ah0 = *(const int4*)(hsb + base + (size_t)(s0+srow)*HH    + k0 + skc*8);
    int4 ah1 = *(const int4*)(hsb + base + (size_t)(s0+srow+64)*HH + k0 + skc*8);
    int4 al0 = *(const int4*)(hsl + base + (size_t)(s0+srow)*HH    + k0 + skc*8);
    int4 al1 = *(const int4*)(hsl + base + (size_t)(s0+srow+64)*HH + k0 + skc*8);
    int4 bh0 = *(const int4*)(hsb + base + (size_t)(t0+srow)*HH    + k0 + skc*8);
    int4 bh1 = *(const int4*)(hsb + base + (size_t)(t0+srow+64)*HH + k0 + skc*8);
    int4 bl0 = *(const int4*)(hsl + base + (size_t)(t0+srow)*HH    + k0 + skc*8);
    int4 bl1 = *(const int4*)(hsl + base + (size_t)(t0+srow+64)*HH + k0 + skc*8);
    __syncthreads();
    *(int4*)&Ah[srow][skc*8]    = ah0;  *(int4*)&Ah[srow+64][skc*8] = ah1;
    *(int4*)&Al[srow][skc*8]    = al0;  *(int4*)&Al[srow+64][skc*8] = al1;
    *(int4*)&Bh[srow][skc*8]    = bh0;  *(int4*)&Bh[srow+64][skc*8] = bh1;
    *(int4*)&Bl[srow][skc*8]    = bl0;  *(int4*)&Bl[srow+64][skc*8] = bl1;
    __syncthreads();
    bf16x8 ah[4], al[4], bh[4], bl[4];
    #pragma unroll
    for (int i=0;i<4;i++){
      ah[i] = *(const bf16x8*)&Ah[wm*64 + i*16 + lm][lq*8];
      al[i] = *(const bf16x8*)&Al[wm*64 + i*16 + lm][lq*8];
    }
    #pragma unroll
    for (int j=0;j<4;j++){
      bh[j] = *(const bf16x8*)&Bh[wn*64 + j*16 + lm][lq*8];
      bl[j] = *(const bf16x8*)&Bl[wn*64 + j*16 + lm][lq*8];
    }
    #pragma unroll
    for (int i=0;i<4;i++)
      #pragma unroll
      for (int j=0;j<4;j++){
        acc[i][j] = __builtin_amdgcn_mfma_f32_16x16x32_bf16(ah[i], bh[j], acc[i][j], 0, 0, 0);
        acc[i][j] = __builtin_amdgcn_mfma_f32_16x16x32_bf16(ah[i], bl[j], acc[i][j], 0, 0, 0);
        acc[i][j] = __builtin_amdgcn_mfma_f32_16x16x32_bf16(al[i], bh[j], acc[i][j], 0, 0, 0);
      }
  }
  #pragma unroll
  for (int i=0;i<4;i++){
    #pragma unroll
    for (int j=0;j<4;j++){
      int col = t0 + wn*64 + j*16 + lm;
      #pragma unroll
      for (int r4=0;r4<4;r4++){
        int row = s0 + wm*64 + i*16 + lq*4 + r4;
        sim[((size_t)(b*SS+row))*SS + col] = acc[i][j][r4];
      }
    }
  }
}

// K8: masked row-softmax of sim, column-sums
__global__ __launch_bounds__(256) void k_simsm(const float* __restrict__ sim,
    const int* __restrict__ s1a, const int* __restrict__ s2a,
    float* __restrict__ v1g, float* __restrict__ v2g){
  int b = blockIdx.x;
  int s1 = s1a[b], s2 = s2a[b];
  int tid=threadIdx.x, wave=tid>>6, lane=tid&63;
  __shared__ float av[2][4][SS];
  for (int i=tid;i<2*4*SS;i+=256) ((float*)av)[i]=0.f;
  __syncthreads();
  for (int r = wave; r < SS; r += 4){
    int t0,t1,which;
    if (r>=1 && r<s1){ t0=s1+1; t1=s2; which=0; }
    else if (r>s1 && r<s2){ t0=1; t1=s1; which=1; }
    else continue;
    const float* row = sim + ((size_t)(b*SS+r))*SS;
    float vals[7]; float mx=-1e30f;
    #pragma unroll
    for (int j=0;j<7;j++){
      int t = t0 + lane + 64*j;
      vals[j] = (t<t1) ? row[t] : -1e30f;
      mx = fmaxf(mx, vals[j]);
    }
    mx = wred_max(mx);
    float ssum=0.f;
    #pragma unroll
    for (int j=0;j<7;j++){
      int t = t0+lane+64*j;
      vals[j] = (t<t1)? expf(vals[j]-mx) : 0.f;
      ssum += vals[j];
    }
    ssum = wred_sum(ssum);
    float inv = 1.f/ssum;
    #pragma unroll
    for (int j=0;j<7;j++){
      int t = t0+lane+64*j;
      if (t<t1) av[which][wave][t] += vals[j]*inv;
    }
  }
  __syncthreads();
  for (int t=tid;t<SS;t+=256){
    v1g[b*SS+t] = av[0][0][t]+av[0][1][t]+av[0][2][t]+av[0][3][t];
    v2g[b*SS+t] = av[1][0][t]+av[1][1][t]+av[1][2][t]+av[1][3][t];
  }
}

// K9: align branch (exact fp32)
__global__ __launch_bounds__(256) void k_align(const float* __restrict__ hs,
    const float* __restrict__ v1g, const float* __restrict__ v2g,
    const float* __restrict__ w1, const float* __restrict__ b1,
    const float* __restrict__ w2, const float* __restrict__ b2,
    const float* __restrict__ invnp, const float* __restrict__ invnh, float* __restrict__ comb){
  int b=blockIdx.x, tid=threadIdx.x;
  __shared__ float sv1[SS], sv2[SS];
  __shared__ float cat[2*HH];
  __shared__ float tmp[HH];
  for (int t=tid;t<SS;t+=256){ sv1[t]=v1g[b*SS+t]; sv2[t]=v2g[b*SS+t]; }
  __syncthreads();
  float inp=invnp[b], inh=invnh[b];
  for (int d=tid; d<HH; d+=256){
    float a1=0.f,a2=0.f;
    for (int t=0;t<SS;t++){
      float x = hs[((size_t)(b*SS+t))*HH + d];
      a1 += sv1[t]*x; a2 += sv2[t]*x;
    }
    cat[d]=a1*inp; cat[HH+d]=a2*inh;
  }
  __syncthreads();
  for (int j=tid;j<HH;j+=256){
    float a=b1[j];
    for (int i=0;i<2*HH;i++) a += cat[i]*w1[(size_t)i*HH+j];
    tmp[j]=a;
  }
  __syncthreads();
  if (tid<128){
    float a=b2[tid];
    for (int i=0;i<HH;i++) a += tmp[i]*w2[i*128+tid];
    comb[b*512+384+tid]=telu_f(a);
  }
}

// K10: classifier head
__global__ __launch_bounds__(64) void k_cls(const float* __restrict__ comb,
    const float* __restrict__ w1, const float* __restrict__ b1,
    const float* __restrict__ w2, const float* __restrict__ b2, float* __restrict__ out){
  int b=blockIdx.x, tid=threadIdx.x;
  __shared__ float cb[512];
  __shared__ float t1[64];
  for (int i=tid;i<512;i+=64) cb[i]=comb[b*512+i];
  __syncthreads();
  float a = b1[tid];
  for (int k=0;k<512;k++) a += cb[k]*w1[(size_t)k*64+tid];
  t1[tid]=telu_f(a);
  __syncthreads();
  if (tid<3){
    float o = b2[tid];
    for (int k=0;k<64;k++) o += t1[k]*w2[k*3+tid];
    out[b*3+tid]=o;
  }
}

extern "C" void kernel_launch(void* const* d_in, const int* in_sizes, int n_in,
                              void* d_out, int out_size, void* d_ws, size_t ws_size,
                              hipStream_t stream){
  const float* hs   = (const float*)d_in[0];
  const int*   ids  = (const int*)d_in[1];
  const int*   amask= (const int*)d_in[2];
  const float* fe_w1= (const float*)d_in[3];
  const float* fe_b1= (const float*)d_in[4];
  const float* fe_g = (const float*)d_in[5];
  const float* fe_be= (const float*)d_in[6];
  const float* fe_w2= (const float*)d_in[7];
  const float* fe_b2= (const float*)d_in[8];
  const float* al_w1= (const float*)d_in[9];
  const float* al_b1= (const float*)d_in[10];
  const float* al_w2= (const float*)d_in[11];
  const float* al_b2= (const float*)d_in[12];
  const float* wq   = (const float*)d_in[13];
  const float* bq   = (const float*)d_in[14];
  const float* wk   = (const float*)d_in[15];
  const float* bk   = (const float*)d_in[16];
  const float* wv   = (const float*)d_in[17];
  const float* bv   = (const float*)d_in[18];
  const float* wo   = (const float*)d_in[19];
  const float* bo   = (const float*)d_in[20];
  const float* dpw  = (const float*)d_in[21];
  const float* dpb  = (const float*)d_in[22];
  const float* apw  = (const float*)d_in[23];
  const float* apb  = (const float*)d_in[24];
  const float* clw1 = (const float*)d_in[25];
  const float* clb1 = (const float*)d_in[26];
  const float* clw2 = (const float*)d_in[27];
  const float* clb2 = (const float*)d_in[28];
  float* out = (float*)d_out;

  char* base = (char*)d_ws;
  size_t off = 0;
  auto alloc = [&](size_t bytes)->char*{ char* p = base + off; off += (bytes + 255) & ~(size_t)255; return p; };
  short* hsb  = (short*)alloc((size_t)32*SS*HH*2);
  short* hsl  = (short*)alloc((size_t)32*SS*HH*2);
  short* Wt   = (short*)alloc((size_t)3*HH*HH*2);
  short* qbh  = (short*)alloc((size_t)32*SS*HH*2);
  float* kb   = (float*)alloc((size_t)32*256*HH*4);
  float* vb   = (float*)alloc((size_t)32*256*HH*4);
  float* simb = (float*)alloc((size_t)32*SS*SS*4);
  float* upart= (float*)alloc((size_t)32*8*8*256*4);
  int*   s1a  = (int*)alloc(32*4);
  int*   s2a  = (int*)alloc(32*4);
  float* invnam=(float*)alloc(32*4);
  float* invnp =(float*)alloc(32*4);
  float* invnh =(float*)alloc(32*4);
  float* v1g  = (float*)alloc((size_t)32*SS*4);
  float* v2g  = (float*)alloc((size_t)32*SS*4);
  float* xfe  = (float*)alloc((size_t)32*HH*4);
  float* sdiff= (float*)alloc((size_t)32*HH*4);
  float* comb = (float*)alloc((size_t)32*512*4);

  k_scan<<<dim3(32), dim3(512), 0, stream>>>(ids, amask, s1a, s2a, invnam, invnp, invnh);
  k_cvt<<<dim3(32*SS*HH/(256*8)), dim3(256), 0, stream>>>(hs, hsb, hsl);
  k_wt<<<dim3(24,24,3), dim3(256), 0, stream>>>(wq, wk, wv, Wt);
  k_reps<<<dim3(32,3), dim3(256), 0, stream>>>(hs, amask, s1a, s2a, invnam, invnp, invnh, xfe, sdiff);
  k_feat<<<dim3(32), dim3(512), 0, stream>>>(xfe, fe_w1, fe_b1, fe_g, fe_be, fe_w2, fe_b2, comb);
  k_diff<<<dim3(32), dim3(128), 0, stream>>>(sdiff, dpw, dpb, comb);
  k_qkv_mfma<<<dim3(128,18), dim3(256), 0, stream>>>(hsb, Wt, bq, bk, bv, qbh, kb, vb);
  k_attn<<<dim3(32,8,8), dim3(256), 0, stream>>>(qbh, kb, s1a, s2a, upart);
  k_attnrep<<<dim3(32), dim3(256), 0, stream>>>(upart, vb, wo, bo, apw, apb, s1a, invnh, comb);
  k_sim_mfma<<<dim3(4,4,32), dim3(256), 0, stream>>>(hsb, hsl, s2a, simb);
  k_simsm<<<dim3(32), dim3(256), 0, stream>>>(simb, s1a, s2a, v1g, v2g);
  k_align<<<dim3(32), dim3(256), 0, stream>>>(hs, v1g, v2g, al_w1, al_b1, al_w2, al_b2, invnp, invnh, comb);
  k_cls<<<dim3(32), dim3(64), 0, stream>>>(comb, clw1, clb1, clw2, clb2, out);
}

// Round 3
// 1021.057 us; speedup vs baseline: 2.7550x; 1.7344x over previous
//
#include <hip/hip_runtime.h>
#include <hip/hip_bf16.h>
#include <math.h>

#define SS 512
#define HH 768
#define NEGV -1e9f
#define APAD 100   // attention LDS row stride (shorts): 50 dwords -> 2-way bank aliasing (free)

typedef float f32x4 __attribute__((ext_vector_type(4)));
typedef __bf16 bf16x8 __attribute__((ext_vector_type(8)));

__device__ __forceinline__ float telu_f(float x){ return x * tanhf(expf(x)); }

__device__ __forceinline__ short f2bf(float x){
  __hip_bfloat16 h = __float2bfloat16(x);
  return __builtin_bit_cast(short, h);
}
__device__ __forceinline__ float b2f(short s){
  __hip_bfloat16 h = __builtin_bit_cast(__hip_bfloat16, s);
  return __bfloat162float(h);
}

__device__ __forceinline__ float wred_max(float v){
  #pragma unroll
  for (int o=32;o>0;o>>=1) v = fmaxf(v, __shfl_xor(v, o));
  return v;
}
__device__ __forceinline__ float wred_sum(float v){
  #pragma unroll
  for (int o=32;o>0;o>>=1) v += __shfl_xor(v, o);
  return v;
}

// K0: per-batch SEP scan + mask counts
__global__ __launch_bounds__(512) void k_scan(const int* __restrict__ ids, const int* __restrict__ am,
                       int* s1a, int* s2a, float* invnam, float* invnp, float* invnh){
  int b = blockIdx.x, tid = threadIdx.x;
  __shared__ int mn, mx, cnt;
  if (tid==0){ mn = 1<<30; mx = -1; cnt = 0; }
  __syncthreads();
  int id = ids[b*SS+tid];
  if (id==102){ atomicMin(&mn, tid); atomicMax(&mx, tid); }
  atomicAdd(&cnt, am[b*SS+tid]);
  __syncthreads();
  if (tid==0){
    int s1 = mn; if (s1 > 255) s1 = 255; if (s1 < 1) s1 = 1;
    int s2 = mx; if (s2 < s1+1) s2 = s1+1; if (s2 > 511) s2 = 511;
    s1a[b]=s1; s2a[b]=s2;
    invnam[b] = 1.f/fmaxf((float)cnt, 1e-9f);
    invnp[b]  = 1.f/fmaxf((float)(s1-1), 1e-9f);
    invnh[b]  = 1.f/fmaxf((float)(s2-s1-1), 1e-9f);
  }
}

// K-cvt: hs -> bf16 hi + bf16 lo residual
__global__ __launch_bounds__(256) void k_cvt(const float* __restrict__ hs, short* __restrict__ hsb, short* __restrict__ hsl){
  size_t i = ((size_t)blockIdx.x*256 + threadIdx.x)*8;
  float4 x0 = *(const float4*)(hs+i);
  float4 x1 = *(const float4*)(hs+i+4);
  float xv[8] = {x0.x,x0.y,x0.z,x0.w,x1.x,x1.y,x1.z,x1.w};
  short h[8], l[8];
  #pragma unroll
  for (int j=0;j<8;j++){
    h[j] = f2bf(xv[j]);
    l[j] = f2bf(xv[j] - b2f(h[j]));
  }
  *(int4*)(hsb+i) = *(const int4*)h;
  *(int4*)(hsl+i) = *(const int4*)l;
}

// K-wt: transpose+convert wq/wk/wv -> Wt[which][n][k] bf16
__global__ __launch_bounds__(256) void k_wt(const float* __restrict__ wq, const float* __restrict__ wk,
                                            const float* __restrict__ wv, short* __restrict__ Wt){
  int k0 = blockIdx.x*32, n0 = blockIdx.y*32, which = blockIdx.z;
  const float* W = which==0? wq : (which==1? wk : wv);
  __shared__ float tl[32][33];
  int t = threadIdx.x;
  int r = t>>3, c4 = (t&7)*4;
  float4 v = *(const float4*)(W + (size_t)(k0+r)*HH + n0 + c4);
  tl[r][c4+0]=v.x; tl[r][c4+1]=v.y; tl[r][c4+2]=v.z; tl[r][c4+3]=v.w;
  __syncthreads();
  short4 o;
  o.x = f2bf(tl[c4+0][r]); o.y = f2bf(tl[c4+1][r]);
  o.z = f2bf(tl[c4+2][r]); o.w = f2bf(tl[c4+3][r]);
  *(short4*)(Wt + (size_t)which*HH*HH + (size_t)(n0+r)*HH + k0 + c4) = o;
}

// K1: pooled + masked mean + masked max + prem/hyp means -> xfe, sdiff  (exact fp32)
__global__ __launch_bounds__(256) void k_reps(const float* __restrict__ hs, const int* __restrict__ amask,
     const int* __restrict__ s1a, const int* __restrict__ s2a,
     const float* __restrict__ invnam, const float* __restrict__ invnp, const float* __restrict__ invnh,
     float* __restrict__ xfe, float* __restrict__ sdiff){
  int b = blockIdx.x;
  int h = blockIdx.y*256 + threadIdx.x;
  __shared__ int ams[SS];
  for (int s=threadIdx.x; s<SS; s+=256) ams[s] = amask[b*SS+s];
  __syncthreads();
  int s1 = s1a[b], s2 = s2a[b];
  float sm=0.f, mx=NEGV, sp=0.f, sh=0.f;
  for (int s=0;s<SS;s++){
    float x = hs[((size_t)(b*SS+s))*HH + h];
    if (ams[s] > 0){ sm += x; mx = fmaxf(mx, x); }
    if (s>=1 && s<s1) sp += x;
    if (s>s1 && s<s2) sh += x;
  }
  float pooled = hs[((size_t)(b*SS))*HH + h];
  xfe[b*HH+h]   = pooled + sm*invnam[b] + mx;
  sdiff[b*HH+h] = fabsf(sp*invnp[b] - sh*invnh[b]);
}

// K2: feature branch
__global__ __launch_bounds__(512) void k_feat(const float* __restrict__ xfe,
    const float* __restrict__ w1, const float* __restrict__ b1,
    const float* __restrict__ g, const float* __restrict__ be,
    const float* __restrict__ w2, const float* __restrict__ b2,
    float* __restrict__ comb){
  int b = blockIdx.x, tid = threadIdx.x;
  __shared__ float x[HH];
  __shared__ float hn[512];
  __shared__ float red[512];
  for (int i=tid;i<HH;i+=512) x[i] = xfe[b*HH+i];
  __syncthreads();
  float hv = b1[tid];
  for (int k=0;k<HH;k++) hv += x[k]*w1[(size_t)k*512 + tid];
  red[tid] = hv; __syncthreads();
  for (int st=256;st>0;st>>=1){ if (tid<st) red[tid]+=red[tid+st]; __syncthreads(); }
  float mean = red[0]*(1.f/512.f);
  __syncthreads();
  float dv = hv-mean; red[tid]=dv*dv; __syncthreads();
  for (int st=256;st>0;st>>=1){ if (tid<st) red[tid]+=red[tid+st]; __syncthreads(); }
  float var = red[0]*(1.f/512.f);
  __syncthreads();
  hn[tid] = dv * (1.f/sqrtf(var + 1e-5f)) * g[tid] + be[tid];
  __syncthreads();
  if (tid < 128){
    float f = b2[tid];
    for (int k=0;k<512;k++) f += hn[k]*w2[k*128+tid];
    comb[b*512+tid] = telu_f(f);
  }
}

// K3: diff branch
__global__ __launch_bounds__(128) void k_diff(const float* __restrict__ sdiff,
    const float* __restrict__ w, const float* __restrict__ bb, float* __restrict__ comb){
  int b=blockIdx.x, tid=threadIdx.x;
  __shared__ float sd[HH];
  for (int i=tid;i<HH;i+=128) sd[i]=sdiff[b*HH+i];
  __syncthreads();
  float f = bb[tid];
  for (int k=0;k<HH;k++) f += sd[k]*w[(size_t)k*128+tid];
  comb[b*512+128+tid] = telu_f(f);
}

// K4: QKV MFMA GEMM, 128x128 tiles, bf16. q,k stored bf16; v fp32 (rows s<256 only).
__global__ __launch_bounds__(256) void k_qkv_mfma(const short* __restrict__ hsb, const short* __restrict__ Wt,
    const float* __restrict__ bq, const float* __restrict__ bk, const float* __restrict__ bv,
    short* __restrict__ qbh, short* __restrict__ kbh, float* __restrict__ vb){
  int rt = blockIdx.x;
  int ct = blockIdx.y;
  int which = ct/6;
  int n0 = (ct - which*6)*128;
  int r0 = rt*128;
  int s0 = r0 & (SS-1);
  int b  = r0 >> 9;
  if (which>0 && s0 >= 256) return;
  const float* bias = which==0? bq : (which==1? bk : bv);
  const short* Wb = Wt + (size_t)which*HH*HH;

  __shared__ short As[128][40];
  __shared__ short Bs[128][40];
  int tid = threadIdx.x;
  int wv_ = tid>>6, lane = tid&63;
  int wm = wv_>>1, wn = wv_&1;
  int lm = lane&15, lq = lane>>4;

  int srow = tid>>2;
  int skc  = tid&3;

  f32x4 acc[4][4];
  #pragma unroll
  for (int i=0;i<4;i++)
    #pragma unroll
    for (int j=0;j<4;j++) acc[i][j] = (f32x4){0.f,0.f,0.f,0.f};

  for (int k0=0;k0<HH;k0+=32){
    int4 a0 = *(const int4*)(hsb + (size_t)(r0+srow)*HH    + k0 + skc*8);
    int4 a1 = *(const int4*)(hsb + (size_t)(r0+srow+64)*HH + k0 + skc*8);
    int4 b0 = *(const int4*)(Wb  + (size_t)(n0+srow)*HH    + k0 + skc*8);
    int4 b1 = *(const int4*)(Wb  + (size_t)(n0+srow+64)*HH + k0 + skc*8);
    __syncthreads();
    *(int4*)&As[srow][skc*8]    = a0;
    *(int4*)&As[srow+64][skc*8] = a1;
    *(int4*)&Bs[srow][skc*8]    = b0;
    *(int4*)&Bs[srow+64][skc*8] = b1;
    __syncthreads();
    bf16x8 af[4], bfv[4];
    #pragma unroll
    for (int i=0;i<4;i++) af[i]  = *(const bf16x8*)&As[wm*64 + i*16 + lm][lq*8];
    #pragma unroll
    for (int j=0;j<4;j++) bfv[j] = *(const bf16x8*)&Bs[wn*64 + j*16 + lm][lq*8];
    #pragma unroll
    for (int i=0;i<4;i++)
      #pragma unroll
      for (int j=0;j<4;j++)
        acc[i][j] = __builtin_amdgcn_mfma_f32_16x16x32_bf16(af[i], bfv[j], acc[i][j], 0, 0, 0);
  }
  #pragma unroll
  for (int i=0;i<4;i++){
    #pragma unroll
    for (int j=0;j<4;j++){
      int col = n0 + wn*64 + j*16 + lm;
      float bcol = bias[col];
      #pragma unroll
      for (int r4=0;r4<4;r4++){
        int row = r0 + wm*64 + i*16 + lq*4 + r4;
        float val = acc[i][j][r4] + bcol;
        if (which==0)      qbh[(size_t)row*HH + col] = f2bf(val);
        else {
          int s = row & (SS-1);
          size_t o = ((size_t)(b*256+s))*HH + col;
          if (which==1) kbh[o] = f2bf(val); else vb[o] = val;
        }
      }
    }
  }
}

// K5: attention via MFMA. Block = (b, head, 64-q chunk). S = Q·K^T, row-softmax in regs,
// aggregate weights u[k] += sum_q p[q][k] via atomicAdd into zeroed uacc.
__global__ __launch_bounds__(256) void k_attn_mfma(const short* __restrict__ qbh, const short* __restrict__ kbh,
    const int* __restrict__ s1a, const int* __restrict__ s2a, float* __restrict__ uacc){
  int b = blockIdx.x, h = blockIdx.y, zc = blockIdx.z;
  int s1 = s1a[b], s2 = s2a[b];
  int qs = s1 + 1 + zc*64;
  if (qs >= s2) return;
  __shared__ short Ks[256*APAD];   // 51200 B
  __shared__ short Qs[64*APAD];    // 12800 B
  int tid = threadIdx.x, wave = tid>>6, lane = tid&63;
  int lm = lane&15, lq = lane>>4;
  // load K rows 0..255 (cols >= s1 masked later)
  for (int i = tid; i < 256*12; i += 256){
    int r = i/12, c = i - r*12;
    *(int4*)&Ks[r*APAD + c*8] = *(const int4*)(kbh + ((size_t)(b*256+r))*HH + h*96 + c*8);
  }
  // load Q rows qs..qs+63 (guard q<SS)
  for (int i = tid; i < 64*12; i += 256){
    int r = i/12, c = i - r*12;
    int q = qs + r;
    int4 v = {0,0,0,0};
    if (q < SS) v = *(const int4*)(qbh + ((size_t)(b*SS+q))*HH + h*96 + c*8);
    *(int4*)&Qs[r*APAD + c*8] = v;
  }
  __syncthreads();
  f32x4 acc[16];
  #pragma unroll
  for (int j=0;j<16;j++) acc[j] = (f32x4){0.f,0.f,0.f,0.f};
  #pragma unroll
  for (int ks=0; ks<3; ks++){
    bf16x8 a = *(const bf16x8*)&Qs[(wave*16+lm)*APAD + ks*32 + lq*8];
    #pragma unroll
    for (int j=0;j<16;j++){
      bf16x8 bfr = *(const bf16x8*)&Ks[(j*16+lm)*APAD + ks*32 + lq*8];
      acc[j] = __builtin_amdgcn_mfma_f32_16x16x32_bf16(a, bfr, acc[j], 0, 0, 0);
    }
  }
  // softmax per q-row; accumulate u
  const float scale = 0.1020620726f;   // 1/sqrt(96)
  float uj[16];
  #pragma unroll
  for (int j=0;j<16;j++) uj[j]=0.f;
  int qrow_base = qs + wave*16 + lq*4;
  #pragma unroll
  for (int r=0;r<4;r++){
    float m = -1e30f;
    float sc[16];
    #pragma unroll
    for (int j=0;j<16;j++){
      int c = j*16 + lm;
      float s = (c>=1 && c<s1) ? acc[j][r]*scale : -1e30f;
      sc[j] = s; m = fmaxf(m, s);
    }
    #pragma unroll
    for (int o=1;o<16;o<<=1) m = fmaxf(m, __shfl_xor(m, o));
    float ssum = 0.f;
    #pragma unroll
    for (int j=0;j<16;j++){ float p = expf(sc[j]-m); sc[j]=p; ssum += p; }
    #pragma unroll
    for (int o=1;o<16;o<<=1) ssum += __shfl_xor(ssum, o);
    bool rvalid = (qrow_base + r) < s2;
    float inv = rvalid ? 1.f/ssum : 0.f;
    #pragma unroll
    for (int j=0;j<16;j++) uj[j] += sc[j]*inv;
  }
  #pragma unroll
  for (int j=0;j<16;j++){
    float v = uj[j];
    v += __shfl_xor(v, 16);
    v += __shfl_xor(v, 32);
    if (lq==0 && v != 0.f)
      atomicAdd(&uacc[((size_t)(b*8+h))*256 + j*16 + lm], v);
  }
}

// K6: attn_rep finish
__global__ __launch_bounds__(256) void k_attnrep(const float* __restrict__ uacc, const float* __restrict__ vb,
    const float* __restrict__ wo, const float* __restrict__ bo,
    const float* __restrict__ apw, const float* __restrict__ apb,
    const int* __restrict__ s1a, const float* __restrict__ invnh, float* __restrict__ comb){
  int b=blockIdx.x, tid=threadIdx.x;
  int s1=s1a[b]; int nk=s1-1;
  float inh = invnh[b];
  __shared__ float us[8][256];
  __shared__ float cm[HH];
  __shared__ float acc[HH];
  for (int idx=tid; idx<2048; idx+=256){
    int h = idx>>8, sl = idx&255;
    us[h][sl] = uacc[((size_t)(b*8+h))*256 + sl];
  }
  __syncthreads();
  for (int i=tid;i<HH;i+=256){
    int h=i/96;
    float a=0.f;
    for (int sl=0; sl<nk; sl++) a += us[h][sl+1]*vb[((size_t)(b*256+sl+1))*HH + i];
    cm[i]=a*inh;
  }
  __syncthreads();
  for (int j=tid;j<HH;j+=256){
    float a = bo[j];
    for (int i=0;i<HH;i++) a += cm[i]*wo[(size_t)i*HH+j];
    acc[j]=a;
  }
  __syncthreads();
  if (tid<128){
    float a = apb[tid];
    for (int i=0;i<HH;i++) a += acc[i]*apw[(size_t)i*128+tid];
    comb[b*512+256+tid]=telu_f(a);
  }
}

// K7: sim = hs@hs^T via split-precision bf16 MFMA (hi*hi + hi*lo + lo*hi)
__global__ __launch_bounds__(256) void k_sim_mfma(const short* __restrict__ hsb, const short* __restrict__ hsl,
    const int* __restrict__ s2a, float* __restrict__ sim){
  int b = blockIdx.z;
  int s0 = blockIdx.x*128, t0 = blockIdx.y*128;
  int s2 = s2a[b];
  if (s0 >= s2 || t0 >= s2) return;
  __shared__ short Ah[128][40];
  __shared__ short Al[128][40];
  __shared__ short Bh[128][40];
  __shared__ short Bl[128][40];
  int tid = threadIdx.x;
  int wv_ = tid>>6, lane = tid&63;
  int wm = wv_>>1, wn = wv_&1;
  int lm = lane&15, lq = lane>>4;
  int srow = tid>>2, skc = tid&3;
  const size_t base = (size_t)b*SS*HH;

  f32x4 acc[4][4];
  #pragma unroll
  for (int i=0;i<4;i++)
    #pragma unroll
    for (int j=0;j<4;j++) acc[i][j] = (f32x4){0.f,0.f,0.f,0.f};

  for (int k0=0;k0<HH;k0+=32){
    int4 ah0 = *(const int4*)(hsb + base + (size_t)(s0+srow)*HH    + k0 + skc*8);
    int4 ah1 = *(const int4*)(hsb + base + (size_t)(s0+srow+64)*HH + k0 + skc*8);
    int4 al0 = *(const int4*)(hsl + base + (size_t)(s0+srow)*HH    + k0 + skc*8);
    int4 al1 = *(const int4*)(hsl + base + (size_t)(s0+srow+64)*HH + k0 + skc*8);
    int4 bh0 = *(const int4*)(hsb + base + (size_t)(t0+srow)*HH    + k0 + skc*8);
    int4 bh1 = *(const int4*)(hsb + base + (size_t)(t0+srow+64)*HH + k0 + skc*8);
    int4 bl0 = *(const int4*)(hsl + base + (size_t)(t0+srow)*HH    + k0 + skc*8);
    int4 bl1 = *(const int4*)(hsl + base + (size_t)(t0+srow+64)*HH + k0 + skc*8);
    __syncthreads();
    *(int4*)&Ah[srow][skc*8]    = ah0;  *(int4*)&Ah[srow+64][skc*8] = ah1;
    *(int4*)&Al[srow][skc*8]    = al0;  *(int4*)&Al[srow+64][skc*8] = al1;
    *(int4*)&Bh[srow][skc*8]    = bh0;  *(int4*)&Bh[srow+64][skc*8] = bh1;
    *(int4*)&Bl[srow][skc*8]    = bl0;  *(int4*)&Bl[srow+64][skc*8] = bl1;
    __syncthreads();
    bf16x8 ah[4], al[4], bh[4], bl[4];
    #pragma unroll
    for (int i=0;i<4;i++){
      ah[i] = *(const bf16x8*)&Ah[wm*64 + i*16 + lm][lq*8];
      al[i] = *(const bf16x8*)&Al[wm*64 + i*16 + lm][lq*8];
    }
    #pragma unroll
    for (int j=0;j<4;j++){
      bh[j] = *(const bf16x8*)&Bh[wn*64 + j*16 + lm][lq*8];
      bl[j] = *(const bf16x8*)&Bl[wn*64 + j*16 + lm][lq*8];
    }
    #pragma unroll
    for (int i=0;i<4;i++)
      #pragma unroll
      for (int j=0;j<4;j++){
        acc[i][j] = __builtin_amdgcn_mfma_f32_16x16x32_bf16(ah[i], bh[j], acc[i][j], 0, 0, 0);
        acc[i][j] = __builtin_amdgcn_mfma_f32_16x16x32_bf16(ah[i], bl[j], acc[i][j], 0, 0, 0);
        acc[i][j] = __builtin_amdgcn_mfma_f32_16x16x32_bf16(al[i], bh[j], acc[i][j], 0, 0, 0);
      }
  }
  #pragma unroll
  for (int i=0;i<4;i++){
    #pragma unroll
    for (int j=0;j<4;j++){
      int col = t0 + wn*64 + j*16 + lm;
      #pragma unroll
      for (int r4=0;r4<4;r4++){
        int row = s0 + wm*64 + i*16 + lq*4 + r4;
        sim[((size_t)(b*SS+row))*SS + col] = acc[i][j][r4];
      }
    }
  }
}

// K8: masked row-softmax of sim, column-sums; row-range split 8x, atomicAdd into zeroed v1g/v2g
__global__ __launch_bounds__(256) void k_simsm(const float* __restrict__ sim,
    const int* __restrict__ s1a, const int* __restrict__ s2a,
    float* __restrict__ v1g, float* __restrict__ v2g){
  int b = blockIdx.x, cy = blockIdx.y;
  int s1 = s1a[b], s2 = s2a[b];
  int r0 = cy*64;
  int tid=threadIdx.x, wave=tid>>6, lane=tid&63;
  __shared__ float av[2][4][SS];
  for (int i=tid;i<2*4*SS;i+=256) ((float*)av)[i]=0.f;
  __syncthreads();
  for (int r = r0 + wave; r < r0+64; r += 4){
    int t0,t1,which;
    if (r>=1 && r<s1){ t0=s1+1; t1=s2; which=0; }
    else if (r>s1 && r<s2){ t0=1; t1=s1; which=1; }
    else continue;
    const float* row = sim + ((size_t)(b*SS+r))*SS;
    float vals[7]; float mx=-1e30f;
    #pragma unroll
    for (int j=0;j<7;j++){
      int t = t0 + lane + 64*j;
      vals[j] = (t<t1) ? row[t] : -1e30f;
      mx = fmaxf(mx, vals[j]);
    }
    mx = wred_max(mx);
    float ssum=0.f;
    #pragma unroll
    for (int j=0;j<7;j++){
      int t = t0+lane+64*j;
      vals[j] = (t<t1)? expf(vals[j]-mx) : 0.f;
      ssum += vals[j];
    }
    ssum = wred_sum(ssum);
    float inv = 1.f/ssum;
    #pragma unroll
    for (int j=0;j<7;j++){
      int t = t0+lane+64*j;
      if (t<t1) av[which][wave][t] += vals[j]*inv;
    }
  }
  __syncthreads();
  for (int t=tid;t<SS;t+=256){
    float a0 = av[0][0][t]+av[0][1][t]+av[0][2][t]+av[0][3][t];
    float a1 = av[1][0][t]+av[1][1][t]+av[1][2][t]+av[1][3][t];
    if (a0 != 0.f) atomicAdd(&v1g[b*SS+t], a0);
    if (a1 != 0.f) atomicAdd(&v2g[b*SS+t], a1);
  }
}

// K9: align branch (exact fp32)
__global__ __launch_bounds__(256) void k_align(const float* __restrict__ hs,
    const float* __restrict__ v1g, const float* __restrict__ v2g,
    const float* __restrict__ w1, const float* __restrict__ b1,
    const float* __restrict__ w2, const float* __restrict__ b2,
    const float* __restrict__ invnp, const float* __restrict__ invnh, float* __restrict__ comb){
  int b=blockIdx.x, tid=threadIdx.x;
  __shared__ float sv1[SS], sv2[SS];
  __shared__ float cat[2*HH];
  __shared__ float tmp[HH];
  for (int t=tid;t<SS;t+=256){ sv1[t]=v1g[b*SS+t]; sv2[t]=v2g[b*SS+t]; }
  __syncthreads();
  float inp=invnp[b], inh=invnh[b];
  for (int d=tid; d<HH; d+=256){
    float a1=0.f,a2=0.f;
    for (int t=0;t<SS;t++){
      float x = hs[((size_t)(b*SS+t))*HH + d];
      a1 += sv1[t]*x; a2 += sv2[t]*x;
    }
    cat[d]=a1*inp; cat[HH+d]=a2*inh;
  }
  __syncthreads();
  for (int j=tid;j<HH;j+=256){
    float a=b1[j];
    for (int i=0;i<2*HH;i++) a += cat[i]*w1[(size_t)i*HH+j];
    tmp[j]=a;
  }
  __syncthreads();
  if (tid<128){
    float a=b2[tid];
    for (int i=0;i<HH;i++) a += tmp[i]*w2[i*128+tid];
    comb[b*512+384+tid]=telu_f(a);
  }
}

// K10: classifier head
__global__ __launch_bounds__(64) void k_cls(const float* __restrict__ comb,
    const float* __restrict__ w1, const float* __restrict__ b1,
    const float* __restrict__ w2, const float* __restrict__ b2, float* __restrict__ out){
  int b=blockIdx.x, tid=threadIdx.x;
  __shared__ float cb[512];
  __shared__ float t1[64];
  for (int i=tid;i<512;i+=64) cb[i]=comb[b*512+i];
  __syncthreads();
  float a = b1[tid];
  for (int k=0;k<512;k++) a += cb[k]*w1[(size_t)k*64+tid];
  t1[tid]=telu_f(a);
  __syncthreads();
  if (tid<3){
    float o = b2[tid];
    for (int k=0;k<64;k++) o += t1[k]*w2[k*3+tid];
    out[b*3+tid]=o;
  }
}

extern "C" void kernel_launch(void* const* d_in, const int* in_sizes, int n_in,
                              void* d_out, int out_size, void* d_ws, size_t ws_size,
                              hipStream_t stream){
  const float* hs   = (const float*)d_in[0];
  const int*   ids  = (const int*)d_in[1];
  const int*   amask= (const int*)d_in[2];
  const float* fe_w1= (const float*)d_in[3];
  const float* fe_b1= (const float*)d_in[4];
  const float* fe_g = (const float*)d_in[5];
  const float* fe_be= (const float*)d_in[6];
  const float* fe_w2= (const float*)d_in[7];
  const float* fe_b2= (const float*)d_in[8];
  const float* al_w1= (const float*)d_in[9];
  const float* al_b1= (const float*)d_in[10];
  const float* al_w2= (const float*)d_in[11];
  const float* al_b2= (const float*)d_in[12];
  const float* wq   = (const float*)d_in[13];
  const float* bq   = (const float*)d_in[14];
  const float* wk   = (const float*)d_in[15];
  const float* bk   = (const float*)d_in[16];
  const float* wv   = (const float*)d_in[17];
  const float* bv   = (const float*)d_in[18];
  const float* wo   = (const float*)d_in[19];
  const float* bo   = (const float*)d_in[20];
  const float* dpw  = (const float*)d_in[21];
  const float* dpb  = (const float*)d_in[22];
  const float* apw  = (const float*)d_in[23];
  const float* apb  = (const float*)d_in[24];
  const float* clw1 = (const float*)d_in[25];
  const float* clb1 = (const float*)d_in[26];
  const float* clw2 = (const float*)d_in[27];
  const float* clb2 = (const float*)d_in[28];
  float* out = (float*)d_out;

  char* base = (char*)d_ws;
  size_t off = 0;
  auto alloc = [&](size_t bytes)->char*{ char* p = base + off; off += (bytes + 255) & ~(size_t)255; return p; };
  short* hsb  = (short*)alloc((size_t)32*SS*HH*2);
  short* hsl  = (short*)alloc((size_t)32*SS*HH*2);
  short* Wt   = (short*)alloc((size_t)3*HH*HH*2);
  short* qbh  = (short*)alloc((size_t)32*SS*HH*2);
  short* kbh  = (short*)alloc((size_t)32*256*HH*2);
  float* vb   = (float*)alloc((size_t)32*256*HH*4);
  float* simb = (float*)alloc((size_t)32*SS*SS*4);
  float* uacc = (float*)alloc((size_t)32*8*256*4);       // zeroed
  float* v1g  = (float*)alloc((size_t)32*SS*4);          // zeroed (contiguous with uacc)
  float* v2g  = (float*)alloc((size_t)32*SS*4);          // zeroed (contiguous)
  int*   s1a  = (int*)alloc(32*4);
  int*   s2a  = (int*)alloc(32*4);
  float* invnam=(float*)alloc(32*4);
  float* invnp =(float*)alloc(32*4);
  float* invnh =(float*)alloc(32*4);
  float* xfe  = (float*)alloc((size_t)32*HH*4);
  float* sdiff= (float*)alloc((size_t)32*HH*4);
  float* comb = (float*)alloc((size_t)32*512*4);

  // zero the atomic accumulators (uacc + v1g + v2g are contiguous, 256-aligned sizes)
  hipMemsetAsync(uacc, 0, (size_t)(32*8*256 + 32*SS + 32*SS)*4, stream);

  k_scan<<<dim3(32), dim3(512), 0, stream>>>(ids, amask, s1a, s2a, invnam, invnp, invnh);
  k_cvt<<<dim3(32*SS*HH/(256*8)), dim3(256), 0, stream>>>(hs, hsb, hsl);
  k_wt<<<dim3(24,24,3), dim3(256), 0, stream>>>(wq, wk, wv, Wt);
  k_reps<<<dim3(32,3), dim3(256), 0, stream>>>(hs, amask, s1a, s2a, invnam, invnp, invnh, xfe, sdiff);
  k_feat<<<dim3(32), dim3(512), 0, stream>>>(xfe, fe_w1, fe_b1, fe_g, fe_be, fe_w2, fe_b2, comb);
  k_diff<<<dim3(32), dim3(128), 0, stream>>>(sdiff, dpw, dpb, comb);
  k_qkv_mfma<<<dim3(128,18), dim3(256), 0, stream>>>(hsb, Wt, bq, bk, bv, qbh, kbh, vb);
  k_attn_mfma<<<dim3(32,8,8), dim3(256), 0, stream>>>(qbh, kbh, s1a, s2a, uacc);
  k_attnrep<<<dim3(32), dim3(256), 0, stream>>>(uacc, vb, wo, bo, apw, apb, s1a, invnh, comb);
  k_sim_mfma<<<dim3(4,4,32), dim3(256), 0, stream>>>(hsb, hsl, s2a, simb);
  k_simsm<<<dim3(32,8), dim3(256), 0, stream>>>(simb, s1a, s2a, v1g, v2g);
  k_align<<<dim3(32), dim3(256), 0, stream>>>(hs, v1g, v2g, al_w1, al_b1, al_w2, al_b2, invnp, invnh, comb);
  k_cls<<<dim3(32), dim3(64), 0, stream>>>(comb, clw1, clb1, clw2, clb2, out);
}

// Round 4
// 653.209 us; speedup vs baseline: 4.3064x; 1.5631x over previous
//
#include <hip/hip_runtime.h>
#include <hip/hip_bf16.h>
#include <math.h>

#define SS 512
#define HH 768
#define NEGV -1e9f
#define APAD 100

typedef float f32x4 __attribute__((ext_vector_type(4)));
typedef __bf16 bf16x8 __attribute__((ext_vector_type(8)));

__device__ __forceinline__ float telu_f(float x){ return x * tanhf(expf(x)); }

__device__ __forceinline__ short f2bf(float x){
  __hip_bfloat16 h = __float2bfloat16(x);
  return __builtin_bit_cast(short, h);
}
__device__ __forceinline__ float b2f(short s){
  __hip_bfloat16 h = __builtin_bit_cast(__hip_bfloat16, s);
  return __bfloat162float(h);
}

__device__ __forceinline__ float wred_max(float v){
  #pragma unroll
  for (int o=32;o>0;o>>=1) v = fmaxf(v, __shfl_xor(v, o));
  return v;
}
__device__ __forceinline__ float wred_sum(float v){
  #pragma unroll
  for (int o=32;o>0;o>>=1) v += __shfl_xor(v, o);
  return v;
}

// K0: per-batch SEP scan + mask counts
__global__ __launch_bounds__(512) void k_scan(const int* __restrict__ ids, const int* __restrict__ am,
                       int* s1a, int* s2a, float* invnam, float* invnp, float* invnh){
  int b = blockIdx.x, tid = threadIdx.x;
  __shared__ int mn, mx, cnt;
  if (tid==0){ mn = 1<<30; mx = -1; cnt = 0; }
  __syncthreads();
  int id = ids[b*SS+tid];
  if (id==102){ atomicMin(&mn, tid); atomicMax(&mx, tid); }
  atomicAdd(&cnt, am[b*SS+tid]);
  __syncthreads();
  if (tid==0){
    int s1 = mn; if (s1 > 255) s1 = 255; if (s1 < 1) s1 = 1;
    int s2 = mx; if (s2 < s1+1) s2 = s1+1; if (s2 > 511) s2 = 511;
    s1a[b]=s1; s2a[b]=s2;
    invnam[b] = 1.f/fmaxf((float)cnt, 1e-9f);
    invnp[b]  = 1.f/fmaxf((float)(s1-1), 1e-9f);
    invnh[b]  = 1.f/fmaxf((float)(s2-s1-1), 1e-9f);
  }
}

// K-cvt: hs -> bf16 hi + bf16 lo residual
__global__ __launch_bounds__(256) void k_cvt(const float* __restrict__ hs, short* __restrict__ hsb, short* __restrict__ hsl){
  size_t i = ((size_t)blockIdx.x*256 + threadIdx.x)*8;
  float4 x0 = *(const float4*)(hs+i);
  float4 x1 = *(const float4*)(hs+i+4);
  float xv[8] = {x0.x,x0.y,x0.z,x0.w,x1.x,x1.y,x1.z,x1.w};
  short h[8], l[8];
  #pragma unroll
  for (int j=0;j<8;j++){
    h[j] = f2bf(xv[j]);
    l[j] = f2bf(xv[j] - b2f(h[j]));
  }
  *(int4*)(hsb+i) = *(const int4*)h;
  *(int4*)(hsl+i) = *(const int4*)l;
}

// K-wt: transpose+convert wq/wk/wv -> Wt[which][n][k] bf16
__global__ __launch_bounds__(256) void k_wt(const float* __restrict__ wq, const float* __restrict__ wk,
                                            const float* __restrict__ wv, short* __restrict__ Wt){
  int k0 = blockIdx.x*32, n0 = blockIdx.y*32, which = blockIdx.z;
  const float* W = which==0? wq : (which==1? wk : wv);
  __shared__ float tl[32][33];
  int t = threadIdx.x;
  int r = t>>3, c4 = (t&7)*4;
  float4 v = *(const float4*)(W + (size_t)(k0+r)*HH + n0 + c4);
  tl[r][c4+0]=v.x; tl[r][c4+1]=v.y; tl[r][c4+2]=v.z; tl[r][c4+3]=v.w;
  __syncthreads();
  short4 o;
  o.x = f2bf(tl[c4+0][r]); o.y = f2bf(tl[c4+1][r]);
  o.z = f2bf(tl[c4+2][r]); o.w = f2bf(tl[c4+3][r]);
  *(short4*)(Wt + (size_t)which*HH*HH + (size_t)(n0+r)*HH + k0 + c4) = o;
}

// K-reps1: partial reductions over 128-row s-chunks
__global__ __launch_bounds__(256) void k_reps1(const float* __restrict__ hs, const int* __restrict__ amask,
     const int* __restrict__ s1a, const int* __restrict__ s2a, float* __restrict__ repp){
  int b = blockIdx.x, hc = blockIdx.y, sc = blockIdx.z;
  int tid = threadIdx.x;
  int h = hc*256 + tid;
  __shared__ int ams[128];
  int sbase = sc*128;
  for (int s=tid; s<128; s+=256) ams[s] = amask[b*SS + sbase + s];
  __syncthreads();
  int s1 = s1a[b], s2 = s2a[b];
  float sm=0.f, mx=NEGV, sp=0.f, sh=0.f;
  for (int si=0; si<128; si++){
    int s = sbase + si;
    float x = hs[((size_t)(b*SS+s))*HH + h];
    if (ams[si] > 0){ sm += x; mx = fmaxf(mx, x); }
    if (s>=1 && s<s1) sp += x;
    if (s>s1 && s<s2) sh += x;
  }
  float4 o; o.x=sm; o.y=mx; o.z=sp; o.w=sh;
  *(float4*)&repp[(((size_t)(b*3+hc)*4+sc)*256 + tid)*4] = o;
}

// K-reps2: combine partials -> xfe, sdiff
__global__ __launch_bounds__(256) void k_reps2(const float* __restrict__ hs, const float* __restrict__ repp,
     const float* __restrict__ invnam, const float* __restrict__ invnp, const float* __restrict__ invnh,
     float* __restrict__ xfe, float* __restrict__ sdiff){
  int b = blockIdx.x, hc = blockIdx.y;
  int tid = threadIdx.x;
  int h = hc*256 + tid;
  float sm=0.f, mx=NEGV, sp=0.f, sh=0.f;
  #pragma unroll
  for (int sc=0; sc<4; sc++){
    float4 p = *(const float4*)&repp[(((size_t)(b*3+hc)*4+sc)*256 + tid)*4];
    sm += p.x; mx = fmaxf(mx, p.y); sp += p.z; sh += p.w;
  }
  float pooled = hs[((size_t)(b*SS))*HH + h];
  xfe[b*HH+h]   = pooled + sm*invnam[b] + mx;
  sdiff[b*HH+h] = fabsf(sp*invnp[b] - sh*invnh[b]);
}

// Generic batched GEMV: y[b][j] = bias[j] + sum_i x[b][i]*W[i][j]; grid (32, N/128)
template<int K, int N>
__global__ __launch_bounds__(256) void k_bgemv(const float* __restrict__ x, const float* __restrict__ W,
    const float* __restrict__ bias, float* __restrict__ y){
  int b = blockIdx.x, j0 = blockIdx.y*128;
  int tid = threadIdx.x;
  __shared__ float xs[K];
  __shared__ float psum[2][128];
  for (int i=tid;i<K;i+=256) xs[i] = x[(size_t)b*K + i];
  __syncthreads();
  int jj = tid & 127, half = tid >> 7;
  int j = j0 + jj;
  float a = 0.f;
  for (int i = half*(K/2); i < (half+1)*(K/2); i++)
    a += xs[i]*W[(size_t)i*N + j];
  psum[half][jj] = a;
  __syncthreads();
  if (tid < 128)
    y[(size_t)b*N + j0 + tid] = bias[j0+tid] + psum[0][tid] + psum[1][tid];
}

// Generic tail: comb[b][off+j] = telu(bias[j] + sum_i x[b][i]*W[i][j]), x 768-wide, j<128
__global__ __launch_bounds__(256) void k_tail128(const float* __restrict__ x, const float* __restrict__ W,
    const float* __restrict__ bias, float* __restrict__ comb, int off){
  int b = blockIdx.x, tid = threadIdx.x;
  __shared__ float xs[HH];
  __shared__ float psum[2][128];
  for (int i=tid;i<HH;i+=256) xs[i] = x[(size_t)b*HH + i];
  __syncthreads();
  int jj = tid & 127, half = tid >> 7;
  float a = 0.f;
  for (int i = half*384; i < (half+1)*384; i++)
    a += xs[i]*W[(size_t)i*128 + jj];
  psum[half][jj] = a;
  __syncthreads();
  if (tid < 128)
    comb[b*512 + off + tid] = telu_f(bias[tid] + psum[0][tid] + psum[1][tid]);
}

// K-feat2: LN(h) then 512->128 + telu
__global__ __launch_bounds__(256) void k_feat2(const float* __restrict__ featd,
    const float* __restrict__ g, const float* __restrict__ be,
    const float* __restrict__ w2, const float* __restrict__ b2, float* __restrict__ comb){
  int b = blockIdx.x, tid = threadIdx.x;
  __shared__ float hv[512];
  __shared__ float hn[512];
  __shared__ float red[256];
  __shared__ float psum[2][128];
  hv[tid] = featd[(size_t)b*512 + tid];
  hv[tid+256] = featd[(size_t)b*512 + tid + 256];
  __syncthreads();
  red[tid] = hv[tid] + hv[tid+256];
  __syncthreads();
  for (int st=128; st>0; st>>=1){ if (tid<st) red[tid]+=red[tid+st]; __syncthreads(); }
  float mean = red[0]*(1.f/512.f);
  __syncthreads();
  float d0 = hv[tid]-mean, d1 = hv[tid+256]-mean;
  red[tid] = d0*d0 + d1*d1;
  __syncthreads();
  for (int st=128; st>0; st>>=1){ if (tid<st) red[tid]+=red[tid+st]; __syncthreads(); }
  float inv = 1.f/sqrtf(red[0]*(1.f/512.f) + 1e-5f);
  __syncthreads();
  hn[tid]     = d0*inv*g[tid]     + be[tid];
  hn[tid+256] = d1*inv*g[tid+256] + be[tid+256];
  __syncthreads();
  int jj = tid & 127, half = tid >> 7;
  float a = 0.f;
  for (int k = half*256; k < (half+1)*256; k++)
    a += hn[k]*w2[k*128 + jj];
  psum[half][jj] = a;
  __syncthreads();
  if (tid < 128)
    comb[b*512 + tid] = telu_f(b2[tid] + psum[0][tid] + psum[1][tid]);
}

// K4: QKV MFMA GEMM
__global__ __launch_bounds__(256) void k_qkv_mfma(const short* __restrict__ hsb, const short* __restrict__ Wt,
    const float* __restrict__ bq, const float* __restrict__ bk, const float* __restrict__ bv,
    short* __restrict__ qbh, short* __restrict__ kbh, float* __restrict__ vb){
  int rt = blockIdx.x;
  int ct = blockIdx.y;
  int which = ct/6;
  int n0 = (ct - which*6)*128;
  int r0 = rt*128;
  int s0 = r0 & (SS-1);
  int b  = r0 >> 9;
  if (which>0 && s0 >= 256) return;
  const float* bias = which==0? bq : (which==1? bk : bv);
  const short* Wb = Wt + (size_t)which*HH*HH;

  __shared__ short As[128][40];
  __shared__ short Bs[128][40];
  int tid = threadIdx.x;
  int wv_ = tid>>6, lane = tid&63;
  int wm = wv_>>1, wn = wv_&1;
  int lm = lane&15, lq = lane>>4;
  int srow = tid>>2;
  int skc  = tid&3;

  f32x4 acc[4][4];
  #pragma unroll
  for (int i=0;i<4;i++)
    #pragma unroll
    for (int j=0;j<4;j++) acc[i][j] = (f32x4){0.f,0.f,0.f,0.f};

  for (int k0=0;k0<HH;k0+=32){
    int4 a0 = *(const int4*)(hsb + (size_t)(r0+srow)*HH    + k0 + skc*8);
    int4 a1 = *(const int4*)(hsb + (size_t)(r0+srow+64)*HH + k0 + skc*8);
    int4 b0 = *(const int4*)(Wb  + (size_t)(n0+srow)*HH    + k0 + skc*8);
    int4 b1 = *(const int4*)(Wb  + (size_t)(n0+srow+64)*HH + k0 + skc*8);
    __syncthreads();
    *(int4*)&As[srow][skc*8]    = a0;
    *(int4*)&As[srow+64][skc*8] = a1;
    *(int4*)&Bs[srow][skc*8]    = b0;
    *(int4*)&Bs[srow+64][skc*8] = b1;
    __syncthreads();
    bf16x8 af[4], bfv[4];
    #pragma unroll
    for (int i=0;i<4;i++) af[i]  = *(const bf16x8*)&As[wm*64 + i*16 + lm][lq*8];
    #pragma unroll
    for (int j=0;j<4;j++) bfv[j] = *(const bf16x8*)&Bs[wn*64 + j*16 + lm][lq*8];
    #pragma unroll
    for (int i=0;i<4;i++)
      #pragma unroll
      for (int j=0;j<4;j++)
        acc[i][j] = __builtin_amdgcn_mfma_f32_16x16x32_bf16(af[i], bfv[j], acc[i][j], 0, 0, 0);
  }
  #pragma unroll
  for (int i=0;i<4;i++){
    #pragma unroll
    for (int j=0;j<4;j++){
      int col = n0 + wn*64 + j*16 + lm;
      float bcol = bias[col];
      #pragma unroll
      for (int r4=0;r4<4;r4++){
        int row = r0 + wm*64 + i*16 + lq*4 + r4;
        float val = acc[i][j][r4] + bcol;
        if (which==0)      qbh[(size_t)row*HH + col] = f2bf(val);
        else {
          int s = row & (SS-1);
          size_t o = ((size_t)(b*256+s))*HH + col;
          if (which==1) kbh[o] = f2bf(val); else vb[o] = val;
        }
      }
    }
  }
}

// K5: attention via MFMA
__global__ __launch_bounds__(256) void k_attn_mfma(const short* __restrict__ qbh, const short* __restrict__ kbh,
    const int* __restrict__ s1a, const int* __restrict__ s2a, float* __restrict__ uacc){
  int b = blockIdx.x, h = blockIdx.y, zc = blockIdx.z;
  int s1 = s1a[b], s2 = s2a[b];
  int qs = s1 + 1 + zc*64;
  if (qs >= s2) return;
  __shared__ short Ks[256*APAD];
  __shared__ short Qs[64*APAD];
  int tid = threadIdx.x, wave = tid>>6, lane = tid&63;
  int lm = lane&15, lq = lane>>4;
  for (int i = tid; i < 256*12; i += 256){
    int r = i/12, c = i - r*12;
    *(int4*)&Ks[r*APAD + c*8] = *(const int4*)(kbh + ((size_t)(b*256+r))*HH + h*96 + c*8);
  }
  for (int i = tid; i < 64*12; i += 256){
    int r = i/12, c = i - r*12;
    int q = qs + r;
    int4 v = {0,0,0,0};
    if (q < SS) v = *(const int4*)(qbh + ((size_t)(b*SS+q))*HH + h*96 + c*8);
    *(int4*)&Qs[r*APAD + c*8] = v;
  }
  __syncthreads();
  f32x4 acc[16];
  #pragma unroll
  for (int j=0;j<16;j++) acc[j] = (f32x4){0.f,0.f,0.f,0.f};
  #pragma unroll
  for (int ks=0; ks<3; ks++){
    bf16x8 a = *(const bf16x8*)&Qs[(wave*16+lm)*APAD + ks*32 + lq*8];
    #pragma unroll
    for (int j=0;j<16;j++){
      bf16x8 bfr = *(const bf16x8*)&Ks[(j*16+lm)*APAD + ks*32 + lq*8];
      acc[j] = __builtin_amdgcn_mfma_f32_16x16x32_bf16(a, bfr, acc[j], 0, 0, 0);
    }
  }
  const float scale = 0.1020620726f;
  float uj[16];
  #pragma unroll
  for (int j=0;j<16;j++) uj[j]=0.f;
  int qrow_base = qs + wave*16 + lq*4;
  #pragma unroll
  for (int r=0;r<4;r++){
    float m = -1e30f;
    float sc[16];
    #pragma unroll
    for (int j=0;j<16;j++){
      int c = j*16 + lm;
      float s = (c>=1 && c<s1) ? acc[j][r]*scale : -1e30f;
      sc[j] = s; m = fmaxf(m, s);
    }
    #pragma unroll
    for (int o=1;o<16;o<<=1) m = fmaxf(m, __shfl_xor(m, o));
    float ssum = 0.f;
    #pragma unroll
    for (int j=0;j<16;j++){ float p = expf(sc[j]-m); sc[j]=p; ssum += p; }
    #pragma unroll
    for (int o=1;o<16;o<<=1) ssum += __shfl_xor(ssum, o);
    bool rvalid = (qrow_base + r) < s2;
    float inv = rvalid ? 1.f/ssum : 0.f;
    #pragma unroll
    for (int j=0;j<16;j++) uj[j] += sc[j]*inv;
  }
  #pragma unroll
  for (int j=0;j<16;j++){
    float v = uj[j];
    v += __shfl_xor(v, 16);
    v += __shfl_xor(v, 32);
    if (lq==0 && v != 0.f)
      atomicAdd(&uacc[((size_t)(b*8+h))*256 + j*16 + lm], v);
  }
}

// K-ctx: cm[b][i] = inh * sum_sl us[h][sl]*vb[b][sl][i], grid (32, 6)
__global__ __launch_bounds__(256) void k_ctx(const float* __restrict__ uacc, const float* __restrict__ vb,
    const int* __restrict__ s1a, const float* __restrict__ invnh, float* __restrict__ cmg){
  int b = blockIdx.x, i0 = blockIdx.y*128;
  int tid = threadIdx.x;
  int s1 = s1a[b]; int nk = s1-1;
  float inh = invnh[b];
  __shared__ float us[2048];
  __shared__ float psum[2][128];
  for (int idx=tid; idx<2048; idx+=256) us[idx] = uacc[(size_t)b*2048 + idx];
  __syncthreads();
  int ii = tid & 127, half = tid >> 7;
  int i = i0 + ii;
  int h = i/96;
  float a = 0.f;
  int lo = 1 + half*128;
  int hi = nk < (lo+127) ? nk : (lo+127);
  for (int sl=lo; sl<=hi; sl++)
    a += us[h*256+sl]*vb[((size_t)(b*256+sl))*HH + i];
  psum[half][ii] = a;
  __syncthreads();
  if (tid < 128)
    cmg[(size_t)b*HH + i0 + tid] = (psum[0][tid] + psum[1][tid])*inh;
}

// K7: sim = hs@hs^T via split-precision bf16 MFMA
__global__ __launch_bounds__(256) void k_sim_mfma(const short* __restrict__ hsb, const short* __restrict__ hsl,
    const int* __restrict__ s2a, float* __restrict__ sim){
  int b = blockIdx.z;
  int s0 = blockIdx.x*128, t0 = blockIdx.y*128;
  int s2 = s2a[b];
  if (s0 >= s2 || t0 >= s2) return;
  __shared__ short Ah[128][40];
  __shared__ short Al[128][40];
  __shared__ short Bh[128][40];
  __shared__ short Bl[128][40];
  int tid = threadIdx.x;
  int wv_ = tid>>6, lane = tid&63;
  int wm = wv_>>1, wn = wv_&1;
  int lm = lane&15, lq = lane>>4;
  int srow = tid>>2, skc = tid&3;
  const size_t base = (size_t)b*SS*HH;

  f32x4 acc[4][4];
  #pragma unroll
  for (int i=0;i<4;i++)
    #pragma unroll
    for (int j=0;j<4;j++) acc[i][j] = (f32x4){0.f,0.f,0.f,0.f};

  for (int k0=0;k0<HH;k0+=32){
    int4 ah0 = *(const int4*)(hsb + base + (size_t)(s0+srow)*HH    + k0 + skc*8);
    int4 ah1 = *(const int4*)(hsb + base + (size_t)(s0+srow+64)*HH + k0 + skc*8);
    int4 al0 = *(const int4*)(hsl + base + (size_t)(s0+srow)*HH    + k0 + skc*8);
    int4 al1 = *(const int4*)(hsl + base + (size_t)(s0+srow+64)*HH + k0 + skc*8);
    int4 bh0 = *(const int4*)(hsb + base + (size_t)(t0+srow)*HH    + k0 + skc*8);
    int4 bh1 = *(const int4*)(hsb + base + (size_t)(t0+srow+64)*HH + k0 + skc*8);
    int4 bl0 = *(const int4*)(hsl + base + (size_t)(t0+srow)*HH    + k0 + skc*8);
    int4 bl1 = *(const int4*)(hsl + base + (size_t)(t0+srow+64)*HH + k0 + skc*8);
    __syncthreads();
    *(int4*)&Ah[srow][skc*8]    = ah0;  *(int4*)&Ah[srow+64][skc*8] = ah1;
    *(int4*)&Al[srow][skc*8]    = al0;  *(int4*)&Al[srow+64][skc*8] = al1;
    *(int4*)&Bh[srow][skc*8]    = bh0;  *(int4*)&Bh[srow+64][skc*8] = bh1;
    *(int4*)&Bl[srow][skc*8]    = bl0;  *(int4*)&Bl[srow+64][skc*8] = bl1;
    __syncthreads();
    bf16x8 ah[4], al[4], bh[4], bl[4];
    #pragma unroll
    for (int i=0;i<4;i++){
      ah[i] = *(const bf16x8*)&Ah[wm*64 + i*16 + lm][lq*8];
      al[i] = *(const bf16x8*)&Al[wm*64 + i*16 + lm][lq*8];
    }
    #pragma unroll
    for (int j=0;j<4;j++){
      bh[j] = *(const bf16x8*)&Bh[wn*64 + j*16 + lm][lq*8];
      bl[j] = *(const bf16x8*)&Bl[wn*64 + j*16 + lm][lq*8];
    }
    #pragma unroll
    for (int i=0;i<4;i++)
      #pragma unroll
      for (int j=0;j<4;j++){
        acc[i][j] = __builtin_amdgcn_mfma_f32_16x16x32_bf16(ah[i], bh[j], acc[i][j], 0, 0, 0);
        acc[i][j] = __builtin_amdgcn_mfma_f32_16x16x32_bf16(ah[i], bl[j], acc[i][j], 0, 0, 0);
        acc[i][j] = __builtin_amdgcn_mfma_f32_16x16x32_bf16(al[i], bh[j], acc[i][j], 0, 0, 0);
      }
  }
  #pragma unroll
  for (int i=0;i<4;i++){
    #pragma unroll
    for (int j=0;j<4;j++){
      int col = t0 + wn*64 + j*16 + lm;
      #pragma unroll
      for (int r4=0;r4<4;r4++){
        int row = s0 + wm*64 + i*16 + lq*4 + r4;
        sim[((size_t)(b*SS+row))*SS + col] = acc[i][j][r4];
      }
    }
  }
}

// K8: masked row-softmax of sim, column-sums; row-range split 8x
__global__ __launch_bounds__(256) void k_simsm(const float* __restrict__ sim,
    const int* __restrict__ s1a, const int* __restrict__ s2a,
    float* __restrict__ v1g, float* __restrict__ v2g){
  int b = blockIdx.x, cy = blockIdx.y;
  int s1 = s1a[b], s2 = s2a[b];
  int r0 = cy*64;
  int tid=threadIdx.x, wave=tid>>6, lane=tid&63;
  __shared__ float av[2][4][SS];
  for (int i=tid;i<2*4*SS;i+=256) ((float*)av)[i]=0.f;
  __syncthreads();
  for (int r = r0 + wave; r < r0+64; r += 4){
    int t0,t1,which;
    if (r>=1 && r<s1){ t0=s1+1; t1=s2; which=0; }
    else if (r>s1 && r<s2){ t0=1; t1=s1; which=1; }
    else continue;
    const float* row = sim + ((size_t)(b*SS+r))*SS;
    float vals[7]; float mx=-1e30f;
    #pragma unroll
    for (int j=0;j<7;j++){
      int t = t0 + lane + 64*j;
      vals[j] = (t<t1) ? row[t] : -1e30f;
      mx = fmaxf(mx, vals[j]);
    }
    mx = wred_max(mx);
    float ssum=0.f;
    #pragma unroll
    for (int j=0;j<7;j++){
      int t = t0+lane+64*j;
      vals[j] = (t<t1)? expf(vals[j]-mx) : 0.f;
      ssum += vals[j];
    }
    ssum = wred_sum(ssum);
    float inv = 1.f/ssum;
    #pragma unroll
    for (int j=0;j<7;j++){
      int t = t0+lane+64*j;
      if (t<t1) av[which][wave][t] += vals[j]*inv;
    }
  }
  __syncthreads();
  for (int t=tid;t<SS;t+=256){
    float a0 = av[0][0][t]+av[0][1][t]+av[0][2][t]+av[0][3][t];
    float a1 = av[1][0][t]+av[1][1][t]+av[1][2][t]+av[1][3][t];
    if (a0 != 0.f) atomicAdd(&v1g[b*SS+t], a0);
    if (a1 != 0.f) atomicAdd(&v2g[b*SS+t], a1);
  }
}

// K-alvec: cat[b][d] = al1, cat[b][768+d] = al2 ; grid (32, 12), 64 cols each
__global__ __launch_bounds__(256) void k_alvec(const float* __restrict__ hs,
    const float* __restrict__ v1g, const float* __restrict__ v2g,
    const float* __restrict__ invnp, const float* __restrict__ invnh, float* __restrict__ catg){
  int b = blockIdx.x, d0 = blockIdx.y*64;
  int tid = threadIdx.x;
  __shared__ float sv1[SS], sv2[SS];
  __shared__ float p1[4][64], p2[4][64];
  for (int t=tid;t<SS;t+=256){ sv1[t]=v1g[b*SS+t]; sv2[t]=v2g[b*SS+t]; }
  __syncthreads();
  int d = d0 + (tid&63), ch = tid>>6;
  float a1=0.f, a2=0.f;
  for (int t=ch*128; t<ch*128+128; t++){
    float x = hs[((size_t)(b*SS+t))*HH + d];
    a1 += sv1[t]*x; a2 += sv2[t]*x;
  }
  p1[ch][tid&63]=a1; p2[ch][tid&63]=a2;
  __syncthreads();
  if (tid < 64){
    float s1_ = p1[0][tid]+p1[1][tid]+p1[2][tid]+p1[3][tid];
    float s2_ = p2[0][tid]+p2[1][tid]+p2[2][tid]+p2[3][tid];
    catg[(size_t)b*1536 + d0 + tid]       = s1_*invnp[b];
    catg[(size_t)b*1536 + 768 + d0 + tid] = s2_*invnh[b];
  }
}

// K10: classifier head
__global__ __launch_bounds__(64) void k_cls(const float* __restrict__ comb,
    const float* __restrict__ w1, const float* __restrict__ b1,
    const float* __restrict__ w2, const float* __restrict__ b2, float* __restrict__ out){
  int b=blockIdx.x, tid=threadIdx.x;
  __shared__ float cb[512];
  __shared__ float t1[64];
  for (int i=tid;i<512;i+=64) cb[i]=comb[b*512+i];
  __syncthreads();
  float a = b1[tid];
  for (int k=0;k<512;k++) a += cb[k]*w1[(size_t)k*64+tid];
  t1[tid]=telu_f(a);
  __syncthreads();
  if (tid<3){
    float o = b2[tid];
    for (int k=0;k<64;k++) o += t1[k]*w2[k*3+tid];
    out[b*3+tid]=o;
  }
}

extern "C" void kernel_launch(void* const* d_in, const int* in_sizes, int n_in,
                              void* d_out, int out_size, void* d_ws, size_t ws_size,
                              hipStream_t stream){
  const float* hs   = (const float*)d_in[0];
  const int*   ids  = (const int*)d_in[1];
  const int*   amask= (const int*)d_in[2];
  const float* fe_w1= (const float*)d_in[3];
  const float* fe_b1= (const float*)d_in[4];
  const float* fe_g = (const float*)d_in[5];
  const float* fe_be= (const float*)d_in[6];
  const float* fe_w2= (const float*)d_in[7];
  const float* fe_b2= (const float*)d_in[8];
  const float* al_w1= (const float*)d_in[9];
  const float* al_b1= (const float*)d_in[10];
  const float* al_w2= (const float*)d_in[11];
  const float* al_b2= (const float*)d_in[12];
  const float* wq   = (const float*)d_in[13];
  const float* bq   = (const float*)d_in[14];
  const float* wk   = (const float*)d_in[15];
  const float* bk   = (const float*)d_in[16];
  const float* wv   = (const float*)d_in[17];
  const float* bv   = (const float*)d_in[18];
  const float* wo   = (const float*)d_in[19];
  const float* bo   = (const float*)d_in[20];
  const float* dpw  = (const float*)d_in[21];
  const float* dpb  = (const float*)d_in[22];
  const float* apw  = (const float*)d_in[23];
  const float* apb  = (const float*)d_in[24];
  const float* clw1 = (const float*)d_in[25];
  const float* clb1 = (const float*)d_in[26];
  const float* clw2 = (const float*)d_in[27];
  const float* clb2 = (const float*)d_in[28];
  float* out = (float*)d_out;

  char* base = (char*)d_ws;
  size_t off = 0;
  auto alloc = [&](size_t bytes)->char*{ char* p = base + off; off += (bytes + 255) & ~(size_t)255; return p; };
  short* hsb  = (short*)alloc((size_t)32*SS*HH*2);
  short* hsl  = (short*)alloc((size_t)32*SS*HH*2);
  short* Wt   = (short*)alloc((size_t)3*HH*HH*2);
  short* qbh  = (short*)alloc((size_t)32*SS*HH*2);
  short* kbh  = (short*)alloc((size_t)32*256*HH*2);
  float* vb   = (float*)alloc((size_t)32*256*HH*4);
  float* simb = (float*)alloc((size_t)32*SS*SS*4);
  float* uacc = (float*)alloc((size_t)32*8*256*4);       // zeroed
  float* v1g  = (float*)alloc((size_t)32*SS*4);          // zeroed
  float* v2g  = (float*)alloc((size_t)32*SS*4);          // zeroed
  int*   s1a  = (int*)alloc(32*4);
  int*   s2a  = (int*)alloc(32*4);
  float* invnam=(float*)alloc(32*4);
  float* invnp =(float*)alloc(32*4);
  float* invnh =(float*)alloc(32*4);
  float* xfe  = (float*)alloc((size_t)32*HH*4);
  float* sdiff= (float*)alloc((size_t)32*HH*4);
  float* comb = (float*)alloc((size_t)32*512*4);
  float* repp = (float*)alloc((size_t)32*3*4*256*4*4);
  float* featd= (float*)alloc((size_t)32*512*4);
  float* catg = (float*)alloc((size_t)32*1536*4);
  float* tmpg = (float*)alloc((size_t)32*HH*4);
  float* cmg  = (float*)alloc((size_t)32*HH*4);
  float* accg = (float*)alloc((size_t)32*HH*4);

  hipMemsetAsync(uacc, 0, (size_t)(32*8*256 + 32*SS + 32*SS)*4, stream);

  k_scan<<<dim3(32), dim3(512), 0, stream>>>(ids, amask, s1a, s2a, invnam, invnp, invnh);
  k_cvt<<<dim3(32*SS*HH/(256*8)), dim3(256), 0, stream>>>(hs, hsb, hsl);
  k_wt<<<dim3(24,24,3), dim3(256), 0, stream>>>(wq, wk, wv, Wt);
  k_reps1<<<dim3(32,3,4), dim3(256), 0, stream>>>(hs, amask, s1a, s2a, repp);
  k_reps2<<<dim3(32,3), dim3(256), 0, stream>>>(hs, repp, invnam, invnp, invnh, xfe, sdiff);
  k_bgemv<HH,512><<<dim3(32,4), dim3(256), 0, stream>>>(xfe, fe_w1, fe_b1, featd);
  k_feat2<<<dim3(32), dim3(256), 0, stream>>>(featd, fe_g, fe_be, fe_w2, fe_b2, comb);
  k_tail128<<<dim3(32), dim3(256), 0, stream>>>(sdiff, dpw, dpb, comb, 128);
  k_qkv_mfma<<<dim3(128,18), dim3(256), 0, stream>>>(hsb, Wt, bq, bk, bv, qbh, kbh, vb);
  k_attn_mfma<<<dim3(32,8,8), dim3(256), 0, stream>>>(qbh, kbh, s1a, s2a, uacc);
  k_ctx<<<dim3(32,6), dim3(256), 0, stream>>>(uacc, vb, s1a, invnh, cmg);
  k_bgemv<HH,HH><<<dim3(32,6), dim3(256), 0, stream>>>(cmg, wo, bo, accg);
  k_tail128<<<dim3(32), dim3(256), 0, stream>>>(accg, apw, apb, comb, 256);
  k_sim_mfma<<<dim3(4,4,32), dim3(256), 0, stream>>>(hsb, hsl, s2a, simb);
  k_simsm<<<dim3(32,8), dim3(256), 0, stream>>>(simb, s1a, s2a, v1g, v2g);
  k_alvec<<<dim3(32,12), dim3(256), 0, stream>>>(hs, v1g, v2g, invnp, invnh, catg);
  k_bgemv<1536,HH><<<dim3(32,6), dim3(256), 0, stream>>>(catg, al_w1, al_b1, tmpg);
  k_tail128<<<dim3(32), dim3(256), 0, stream>>>(tmpg, al_w2, al_b2, comb, 384);
  k_cls<<<dim3(32), dim3(64), 0, stream>>>(comb, clw1, clb1, clw2, clb2, out);
}

// Round 5
// 609.801 us; speedup vs baseline: 4.6130x; 1.0712x over previous
//
#include <hip/hip_runtime.h>
#include <hip/hip_bf16.h>
#include <math.h>

#define SS 512
#define HH 768
#define NEGV -1e9f
#define APAD 100

typedef float f32x4 __attribute__((ext_vector_type(4)));
typedef __bf16 bf16x8 __attribute__((ext_vector_type(8)));

__device__ __forceinline__ float telu_f(float x){ return x * tanhf(expf(x)); }

__device__ __forceinline__ short f2bf(float x){
  __hip_bfloat16 h = __float2bfloat16(x);
  return __builtin_bit_cast(short, h);
}
__device__ __forceinline__ float b2f(short s){
  __hip_bfloat16 h = __builtin_bit_cast(__hip_bfloat16, s);
  return __bfloat162float(h);
}

__device__ __forceinline__ void gl_lds16(const void* g, void* l){
  __builtin_amdgcn_global_load_lds((const __attribute__((address_space(1))) void*)g,
                                   (__attribute__((address_space(3))) void*)l, 16, 0, 0);
}

__device__ __forceinline__ float wred_max(float v){
  #pragma unroll
  for (int o=32;o>0;o>>=1) v = fmaxf(v, __shfl_xor(v, o));
  return v;
}
__device__ __forceinline__ float wred_sum(float v){
  #pragma unroll
  for (int o=32;o>0;o>>=1) v += __shfl_xor(v, o);
  return v;
}

// K0: per-batch SEP scan + mask counts
__global__ __launch_bounds__(512) void k_scan(const int* __restrict__ ids, const int* __restrict__ am,
                       int* s1a, int* s2a, float* invnam, float* invnp, float* invnh){
  int b = blockIdx.x, tid = threadIdx.x;
  __shared__ int mn, mx, cnt;
  if (tid==0){ mn = 1<<30; mx = -1; cnt = 0; }
  __syncthreads();
  int id = ids[b*SS+tid];
  if (id==102){ atomicMin(&mn, tid); atomicMax(&mx, tid); }
  atomicAdd(&cnt, am[b*SS+tid]);
  __syncthreads();
  if (tid==0){
    int s1 = mn; if (s1 > 255) s1 = 255; if (s1 < 1) s1 = 1;
    int s2 = mx; if (s2 < s1+1) s2 = s1+1; if (s2 > 511) s2 = 511;
    s1a[b]=s1; s2a[b]=s2;
    invnam[b] = 1.f/fmaxf((float)cnt, 1e-9f);
    invnp[b]  = 1.f/fmaxf((float)(s1-1), 1e-9f);
    invnh[b]  = 1.f/fmaxf((float)(s2-s1-1), 1e-9f);
  }
}

// K-prep1: fused hs->bf16 hi/lo conversion + masked partial reductions over 128-row chunks.
// grid (32, 6, 4), block 256. Each block: rows sc*128..+127, cols hc*128..+127.
__global__ __launch_bounds__(256) void k_prep1(const float* __restrict__ hs, const int* __restrict__ amask,
    const int* __restrict__ s1a, const int* __restrict__ s2a,
    short* __restrict__ hsb, short* __restrict__ hsl, float4* __restrict__ repp){
  int b = blockIdx.x, hc = blockIdx.y, sc = blockIdx.z;
  int tid = threadIdx.x;
  __shared__ int ams[128];
  __shared__ float4 rb4[8][128];
  int sbase = sc*128;
  if (tid < 128) ams[tid] = amask[b*SS + sbase + tid];
  __syncthreads();
  int s1 = s1a[b], s2 = s2a[b];
  int hlane = tid & 31, srow = tid >> 5;
  int h0 = hc*128 + hlane*4;
  float sm[4]={0,0,0,0}, sp[4]={0,0,0,0}, sh[4]={0,0,0,0};
  float mxv[4]={NEGV,NEGV,NEGV,NEGV};
  for (int si = srow; si < 128; si += 8){
    int s = sbase + si;
    float4 x = *(const float4*)(hs + ((size_t)(b*SS+s))*HH + h0);
    float xv[4] = {x.x,x.y,x.z,x.w};
    bool am = ams[si] > 0;
    bool ip = (s>=1 && s<s1), ih = (s>s1 && s<s2);
    short hi4[4], lo4[4];
    #pragma unroll
    for (int c=0;c<4;c++){
      if (am){ sm[c]+=xv[c]; mxv[c]=fmaxf(mxv[c],xv[c]); }
      if (ip) sp[c]+=xv[c];
      if (ih) sh[c]+=xv[c];
      hi4[c] = f2bf(xv[c]);
      lo4[c] = f2bf(xv[c] - b2f(hi4[c]));
    }
    *(short4*)(hsb + ((size_t)(b*SS+s))*HH + h0) = *(short4*)hi4;
    *(short4*)(hsl + ((size_t)(b*SS+s))*HH + h0) = *(short4*)lo4;
  }
  #pragma unroll
  for (int c=0;c<4;c++) rb4[srow][hlane*4+c] = make_float4(sm[c], mxv[c], sp[c], sh[c]);
  __syncthreads();
  if (tid < 128){
    float4 a = rb4[0][tid];
    #pragma unroll
    for (int r=1;r<8;r++){
      float4 v = rb4[r][tid];
      a.x += v.x; a.y = fmaxf(a.y, v.y); a.z += v.z; a.w += v.w;
    }
    repp[(((size_t)(b*6+hc))*4 + sc)*128 + tid] = a;
  }
}

// K-prep2: combine 4 s-chunk partials -> xfe, sdiff. grid (32,6), block 128.
__global__ __launch_bounds__(128) void k_prep2(const float* __restrict__ hs, const float4* __restrict__ repp,
    const float* __restrict__ invnam, const float* __restrict__ invnp, const float* __restrict__ invnh,
    float* __restrict__ xfe, float* __restrict__ sdiff){
  int b = blockIdx.x, hc = blockIdx.y, tid = threadIdx.x;
  float S=0.f, M=NEGV, P=0.f, Hh=0.f;
  #pragma unroll
  for (int sc=0; sc<4; sc++){
    float4 v = repp[(((size_t)(b*6+hc))*4 + sc)*128 + tid];
    S += v.x; M = fmaxf(M, v.y); P += v.z; Hh += v.w;
  }
  int h = hc*128 + tid;
  float pooled = hs[((size_t)(b*SS))*HH + h];
  xfe[b*HH+h]   = pooled + S*invnam[b] + M;
  sdiff[b*HH+h] = fabsf(P*invnp[b] - Hh*invnh[b]);
}

// K-wt: transpose+convert wq/wk/wv -> Wt[which][n][k] bf16
__global__ __launch_bounds__(256) void k_wt(const float* __restrict__ wq, const float* __restrict__ wk,
                                            const float* __restrict__ wv, short* __restrict__ Wt){
  int k0 = blockIdx.x*32, n0 = blockIdx.y*32, which = blockIdx.z;
  const float* W = which==0? wq : (which==1? wk : wv);
  __shared__ float tl[32][33];
  int t = threadIdx.x;
  int r = t>>3, c4 = (t&7)*4;
  float4 v = *(const float4*)(W + (size_t)(k0+r)*HH + n0 + c4);
  tl[r][c4+0]=v.x; tl[r][c4+1]=v.y; tl[r][c4+2]=v.z; tl[r][c4+3]=v.w;
  __syncthreads();
  short4 o;
  o.x = f2bf(tl[c4+0][r]); o.y = f2bf(tl[c4+1][r]);
  o.z = f2bf(tl[c4+2][r]); o.w = f2bf(tl[c4+3][r]);
  *(short4*)(Wt + (size_t)which*HH*HH + (size_t)(n0+r)*HH + k0 + c4) = o;
}

// Generic batched GEMV: y[b][j] = bias[j] + sum_i x[b][i]*W[i][j]; grid (32, N/128)
template<int K, int N>
__global__ __launch_bounds__(256) void k_bgemv(const float* __restrict__ x, const float* __restrict__ W,
    const float* __restrict__ bias, float* __restrict__ y){
  int b = blockIdx.x, j0 = blockIdx.y*128;
  int tid = threadIdx.x;
  __shared__ float xs[K];
  __shared__ float psum[2][128];
  for (int i=tid;i<K;i+=256) xs[i] = x[(size_t)b*K + i];
  __syncthreads();
  int jj = tid & 127, half = tid >> 7;
  int j = j0 + jj;
  float a = 0.f;
  for (int i = half*(K/2); i < (half+1)*(K/2); i++)
    a += xs[i]*W[(size_t)i*N + j];
  psum[half][jj] = a;
  __syncthreads();
  if (tid < 128)
    y[(size_t)b*N + j0 + tid] = bias[j0+tid] + psum[0][tid] + psum[1][tid];
}

// Generic tail: comb[b][off+j] = telu(bias[j] + sum_i x[b][i]*W[i][j]), x 768-wide, j<128
__global__ __launch_bounds__(256) void k_tail128(const float* __restrict__ x, const float* __restrict__ W,
    const float* __restrict__ bias, float* __restrict__ comb, int off){
  int b = blockIdx.x, tid = threadIdx.x;
  __shared__ float xs[HH];
  __shared__ float psum[2][128];
  for (int i=tid;i<HH;i+=256) xs[i] = x[(size_t)b*HH + i];
  __syncthreads();
  int jj = tid & 127, half = tid >> 7;
  float a = 0.f;
  for (int i = half*384; i < (half+1)*384; i++)
    a += xs[i]*W[(size_t)i*128 + jj];
  psum[half][jj] = a;
  __syncthreads();
  if (tid < 128)
    comb[b*512 + off + tid] = telu_f(bias[tid] + psum[0][tid] + psum[1][tid]);
}

// K-feat2: LN(h) then 512->128 + telu
__global__ __launch_bounds__(256) void k_feat2(const float* __restrict__ featd,
    const float* __restrict__ g, const float* __restrict__ be,
    const float* __restrict__ w2, const float* __restrict__ b2, float* __restrict__ comb){
  int b = blockIdx.x, tid = threadIdx.x;
  __shared__ float hv[512];
  __shared__ float hn[512];
  __shared__ float red[256];
  __shared__ float psum[2][128];
  hv[tid] = featd[(size_t)b*512 + tid];
  hv[tid+256] = featd[(size_t)b*512 + tid + 256];
  __syncthreads();
  red[tid] = hv[tid] + hv[tid+256];
  __syncthreads();
  for (int st=128; st>0; st>>=1){ if (tid<st) red[tid]+=red[tid+st]; __syncthreads(); }
  float mean = red[0]*(1.f/512.f);
  __syncthreads();
  float d0 = hv[tid]-mean, d1 = hv[tid+256]-mean;
  red[tid] = d0*d0 + d1*d1;
  __syncthreads();
  for (int st=128; st>0; st>>=1){ if (tid<st) red[tid]+=red[tid+st]; __syncthreads(); }
  float inv = 1.f/sqrtf(red[0]*(1.f/512.f) + 1e-5f);
  __syncthreads();
  hn[tid]     = d0*inv*g[tid]     + be[tid];
  hn[tid+256] = d1*inv*g[tid+256] + be[tid+256];
  __syncthreads();
  int jj = tid & 127, half = tid >> 7;
  float a = 0.f;
  for (int k = half*256; k < (half+1)*256; k++)
    a += hn[k]*w2[k*128 + jj];
  psum[half][jj] = a;
  __syncthreads();
  if (tid < 128)
    comb[b*512 + tid] = telu_f(b2[tid] + psum[0][tid] + psum[1][tid]);
}

// K4: QKV MFMA GEMM, m97-style: global_load_lds staging, fragment-major LDS (conflict-free).
// grid: 1536 blocks. id<768: q (rt=id/6); 768..1151: k; 1152..1535: v (rt over 64 half-tiles).
__global__ __launch_bounds__(256) void k_qkv_mfma(const short* __restrict__ hsb, const short* __restrict__ Wt,
    const float* __restrict__ bq, const float* __restrict__ bk, const float* __restrict__ bv,
    short* __restrict__ qbh, short* __restrict__ kbh, float* __restrict__ vb){
  int id = blockIdx.x;
  int which, rem;
  if (id < 768){ which=0; rem=id; }
  else if (id < 1152){ which=1; rem=id-768; }
  else { which=2; rem=id-1152; }
  int rt = rem/6;
  int n0 = (rem - rt*6)*128;
  int r0, b;
  if (which==0){ r0 = rt*128; b = r0>>9; }
  else { b = rt>>1; r0 = b*512 + (rt&1)*128; }
  const float* bias = which==0? bq : (which==1? bk : bv);
  const short* Wb = Wt + (size_t)which*HH*HH;

  __shared__ short As[128*32];   // fragment-major, 8KB
  __shared__ short Bs[128*32];   // 8KB
  int tid = threadIdx.x, lane = tid&63, wave = tid>>6;
  int wm = wave>>1, wn = wave&1;
  int lm = lane&15, lq = lane>>4;

  f32x4 acc[4][4];
  #pragma unroll
  for (int i=0;i<4;i++)
    #pragma unroll
    for (int j=0;j<4;j++) acc[i][j] = (f32x4){0.f,0.f,0.f,0.f};

  for (int k0=0;k0<HH;k0+=32){
    __syncthreads();
    #pragma unroll
    for (int t=0;t<2;t++){
      int c = tid + t*256;
      int ib = c>>6, l = c&63;
      int row = ib*16 + (l&15);
      int kk  = k0 + (l>>4)*8;
      gl_lds16(hsb + (size_t)(r0+row)*HH + kk, As + c*8);
      gl_lds16(Wb  + (size_t)(n0+row)*HH + kk, Bs + c*8);
    }
    __syncthreads();
    bf16x8 af[4], bfv[4];
    #pragma unroll
    for (int i=0;i<4;i++) af[i]  = *(const bf16x8*)&As[((wm*4+i)*64 + lane)*8];
    #pragma unroll
    for (int j=0;j<4;j++) bfv[j] = *(const bf16x8*)&Bs[((wn*4+j)*64 + lane)*8];
    #pragma unroll
    for (int i=0;i<4;i++)
      #pragma unroll
      for (int j=0;j<4;j++)
        acc[i][j] = __builtin_amdgcn_mfma_f32_16x16x32_bf16(af[i], bfv[j], acc[i][j], 0, 0, 0);
  }
  #pragma unroll
  for (int i=0;i<4;i++){
    #pragma unroll
    for (int j=0;j<4;j++){
      int col = n0 + wn*64 + j*16 + lm;
      float bcol = bias[col];
      #pragma unroll
      for (int r4=0;r4<4;r4++){
        int row = r0 + wm*64 + i*16 + lq*4 + r4;
        float val = acc[i][j][r4] + bcol;
        if (which==0)      qbh[(size_t)row*HH + col] = f2bf(val);
        else {
          int s = row & (SS-1);
          size_t o = ((size_t)(b*256+s))*HH + col;
          if (which==1) kbh[o] = f2bf(val); else vb[o] = val;
        }
      }
    }
  }
}

// K5: attention via MFMA
__global__ __launch_bounds__(256) void k_attn_mfma(const short* __restrict__ qbh, const short* __restrict__ kbh,
    const int* __restrict__ s1a, const int* __restrict__ s2a, float* __restrict__ uacc){
  int b = blockIdx.x, h = blockIdx.y, zc = blockIdx.z;
  int s1 = s1a[b], s2 = s2a[b];
  int qs = s1 + 1 + zc*64;
  if (qs >= s2) return;
  __shared__ short Ks[256*APAD];
  __shared__ short Qs[64*APAD];
  int tid = threadIdx.x, wave = tid>>6, lane = tid&63;
  int lm = lane&15, lq = lane>>4;
  for (int i = tid; i < 256*12; i += 256){
    int r = i/12, c = i - r*12;
    *(int4*)&Ks[r*APAD + c*8] = *(const int4*)(kbh + ((size_t)(b*256+r))*HH + h*96 + c*8);
  }
  for (int i = tid; i < 64*12; i += 256){
    int r = i/12, c = i - r*12;
    int q = qs + r;
    int4 v = {0,0,0,0};
    if (q < SS) v = *(const int4*)(qbh + ((size_t)(b*SS+q))*HH + h*96 + c*8);
    *(int4*)&Qs[r*APAD + c*8] = v;
  }
  __syncthreads();
  f32x4 acc[16];
  #pragma unroll
  for (int j=0;j<16;j++) acc[j] = (f32x4){0.f,0.f,0.f,0.f};
  #pragma unroll
  for (int ks=0; ks<3; ks++){
    bf16x8 a = *(const bf16x8*)&Qs[(wave*16+lm)*APAD + ks*32 + lq*8];
    #pragma unroll
    for (int j=0;j<16;j++){
      bf16x8 bfr = *(const bf16x8*)&Ks[(j*16+lm)*APAD + ks*32 + lq*8];
      acc[j] = __builtin_amdgcn_mfma_f32_16x16x32_bf16(a, bfr, acc[j], 0, 0, 0);
    }
  }
  const float scale = 0.1020620726f;
  float uj[16];
  #pragma unroll
  for (int j=0;j<16;j++) uj[j]=0.f;
  int qrow_base = qs + wave*16 + lq*4;
  #pragma unroll
  for (int r=0;r<4;r++){
    float m = -1e30f;
    float sc[16];
    #pragma unroll
    for (int j=0;j<16;j++){
      int c = j*16 + lm;
      float s = (c>=1 && c<s1) ? acc[j][r]*scale : -1e30f;
      sc[j] = s; m = fmaxf(m, s);
    }
    #pragma unroll
    for (int o=1;o<16;o<<=1) m = fmaxf(m, __shfl_xor(m, o));
    float ssum = 0.f;
    #pragma unroll
    for (int j=0;j<16;j++){ float p = expf(sc[j]-m); sc[j]=p; ssum += p; }
    #pragma unroll
    for (int o=1;o<16;o<<=1) ssum += __shfl_xor(ssum, o);
    bool rvalid = (qrow_base + r) < s2;
    float inv = rvalid ? 1.f/ssum : 0.f;
    #pragma unroll
    for (int j=0;j<16;j++) uj[j] += sc[j]*inv;
  }
  #pragma unroll
  for (int j=0;j<16;j++){
    float v = uj[j];
    v += __shfl_xor(v, 16);
    v += __shfl_xor(v, 32);
    if (lq==0 && v != 0.f)
      atomicAdd(&uacc[((size_t)(b*8+h))*256 + j*16 + lm], v);
  }
}

// K-ctx: cm[b][i] = inh * sum_sl us[h][sl]*vb[b][sl][i], grid (32, 6)
__global__ __launch_bounds__(256) void k_ctx(const float* __restrict__ uacc, const float* __restrict__ vb,
    const int* __restrict__ s1a, const float* __restrict__ invnh, float* __restrict__ cmg){
  int b = blockIdx.x, i0 = blockIdx.y*128;
  int tid = threadIdx.x;
  int s1 = s1a[b]; int nk = s1-1;
  float inh = invnh[b];
  __shared__ float us[2048];
  __shared__ float psum[2][128];
  for (int idx=tid; idx<2048; idx+=256) us[idx] = uacc[(size_t)b*2048 + idx];
  __syncthreads();
  int ii = tid & 127, half = tid >> 7;
  int i = i0 + ii;
  int h = i/96;
  float a = 0.f;
  int lo = 1 + half*128;
  int hi = nk < (lo+127) ? nk : (lo+127);
  for (int sl=lo; sl<=hi; sl++)
    a += us[h*256+sl]*vb[((size_t)(b*256+sl))*HH + i];
  psum[half][ii] = a;
  __syncthreads();
  if (tid < 128)
    cmg[(size_t)b*HH + i0 + tid] = (psum[0][tid] + psum[1][tid])*inh;
}

// K7: sim = hs@hs^T via split-precision bf16 MFMA; global_load_lds fragment-major staging.
__global__ __launch_bounds__(256) void k_sim_mfma(const short* __restrict__ hsb, const short* __restrict__ hsl,
    const int* __restrict__ s2a, float* __restrict__ sim){
  int b = blockIdx.z;
  int s0 = blockIdx.x*128, t0 = blockIdx.y*128;
  int s2 = s2a[b];
  if (s0 >= s2 || t0 >= s2) return;
  __shared__ short Ah[128*32];
  __shared__ short Al[128*32];
  __shared__ short Bh[128*32];
  __shared__ short Bl[128*32];
  int tid = threadIdx.x, lane = tid&63, wave = tid>>6;
  int wm = wave>>1, wn = wave&1;
  int lm = lane&15, lq = lane>>4;
  const size_t base = (size_t)b*SS*HH;

  f32x4 acc[4][4];
  #pragma unroll
  for (int i=0;i<4;i++)
    #pragma unroll
    for (int j=0;j<4;j++) acc[i][j] = (f32x4){0.f,0.f,0.f,0.f};

  for (int k0=0;k0<HH;k0+=32){
    __syncthreads();
    #pragma unroll
    for (int t=0;t<2;t++){
      int c = tid + t*256;
      int ib = c>>6, l = c&63;
      int row = ib*16 + (l&15);
      int kk  = k0 + (l>>4)*8;
      gl_lds16(hsb + base + (size_t)(s0+row)*HH + kk, Ah + c*8);
      gl_lds16(hsl + base + (size_t)(s0+row)*HH + kk, Al + c*8);
      gl_lds16(hsb + base + (size_t)(t0+row)*HH + kk, Bh + c*8);
      gl_lds16(hsl + base + (size_t)(t0+row)*HH + kk, Bl + c*8);
    }
    __syncthreads();
    bf16x8 ah[4], al[4], bh[4], bl[4];
    #pragma unroll
    for (int i=0;i<4;i++){
      ah[i] = *(const bf16x8*)&Ah[((wm*4+i)*64 + lane)*8];
      al[i] = *(const bf16x8*)&Al[((wm*4+i)*64 + lane)*8];
    }
    #pragma unroll
    for (int j=0;j<4;j++){
      bh[j] = *(const bf16x8*)&Bh[((wn*4+j)*64 + lane)*8];
      bl[j] = *(const bf16x8*)&Bl[((wn*4+j)*64 + lane)*8];
    }
    #pragma unroll
    for (int i=0;i<4;i++)
      #pragma unroll
      for (int j=0;j<4;j++){
        acc[i][j] = __builtin_amdgcn_mfma_f32_16x16x32_bf16(ah[i], bh[j], acc[i][j], 0, 0, 0);
        acc[i][j] = __builtin_amdgcn_mfma_f32_16x16x32_bf16(ah[i], bl[j], acc[i][j], 0, 0, 0);
        acc[i][j] = __builtin_amdgcn_mfma_f32_16x16x32_bf16(al[i], bh[j], acc[i][j], 0, 0, 0);
      }
  }
  #pragma unroll
  for (int i=0;i<4;i++){
    #pragma unroll
    for (int j=0;j<4;j++){
      int col = t0 + wn*64 + j*16 + lm;
      #pragma unroll
      for (int r4=0;r4<4;r4++){
        int row = s0 + wm*64 + i*16 + lq*4 + r4;
        sim[((size_t)(b*SS+row))*SS + col] = acc[i][j][r4];
      }
    }
  }
}

// K8: masked row-softmax of sim, column-sums; row-range split 8x
__global__ __launch_bounds__(256) void k_simsm(const float* __restrict__ sim,
    const int* __restrict__ s1a, const int* __restrict__ s2a,
    float* __restrict__ v1g, float* __restrict__ v2g){
  int b = blockIdx.x, cy = blockIdx.y;
  int s1 = s1a[b], s2 = s2a[b];
  int r0 = cy*64;
  int tid=threadIdx.x, wave=tid>>6, lane=tid&63;
  __shared__ float av[2][4][SS];
  for (int i=tid;i<2*4*SS;i+=256) ((float*)av)[i]=0.f;
  __syncthreads();
  for (int r = r0 + wave; r < r0+64; r += 4){
    int t0,t1,which;
    if (r>=1 && r<s1){ t0=s1+1; t1=s2; which=0; }
    else if (r>s1 && r<s2){ t0=1; t1=s1; which=1; }
    else continue;
    const float* row = sim + ((size_t)(b*SS+r))*SS;
    float vals[7]; float mx=-1e30f;
    #pragma unroll
    for (int j=0;j<7;j++){
      int t = t0 + lane + 64*j;
      vals[j] = (t<t1) ? row[t] : -1e30f;
      mx = fmaxf(mx, vals[j]);
    }
    mx = wred_max(mx);
    float ssum=0.f;
    #pragma unroll
    for (int j=0;j<7;j++){
      int t = t0+lane+64*j;
      vals[j] = (t<t1)? expf(vals[j]-mx) : 0.f;
      ssum += vals[j];
    }
    ssum = wred_sum(ssum);
    float inv = 1.f/ssum;
    #pragma unroll
    for (int j=0;j<7;j++){
      int t = t0+lane+64*j;
      if (t<t1) av[which][wave][t] += vals[j]*inv;
    }
  }
  __syncthreads();
  for (int t=tid;t<SS;t+=256){
    float a0 = av[0][0][t]+av[0][1][t]+av[0][2][t]+av[0][3][t];
    float a1 = av[1][0][t]+av[1][1][t]+av[1][2][t]+av[1][3][t];
    if (a0 != 0.f) atomicAdd(&v1g[b*SS+t], a0);
    if (a1 != 0.f) atomicAdd(&v2g[b*SS+t], a1);
  }
}

// K-alvec: cat[b][d] = al1, cat[b][768+d] = al2 ; grid (32, 12), 64 cols each
__global__ __launch_bounds__(256) void k_alvec(const float* __restrict__ hs,
    const float* __restrict__ v1g, const float* __restrict__ v2g,
    const float* __restrict__ invnp, const float* __restrict__ invnh, float* __restrict__ catg){
  int b = blockIdx.x, d0 = blockIdx.y*64;
  int tid = threadIdx.x;
  __shared__ float sv1[SS], sv2[SS];
  __shared__ float p1[4][64], p2[4][64];
  for (int t=tid;t<SS;t+=256){ sv1[t]=v1g[b*SS+t]; sv2[t]=v2g[b*SS+t]; }
  __syncthreads();
  int d = d0 + (tid&63), ch = tid>>6;
  float a1=0.f, a2=0.f;
  for (int t=ch*128; t<ch*128+128; t++){
    float x = hs[((size_t)(b*SS+t))*HH + d];
    a1 += sv1[t]*x; a2 += sv2[t]*x;
  }
  p1[ch][tid&63]=a1; p2[ch][tid&63]=a2;
  __syncthreads();
  if (tid < 64){
    float s1_ = p1[0][tid]+p1[1][tid]+p1[2][tid]+p1[3][tid];
    float s2_ = p2[0][tid]+p2[1][tid]+p2[2][tid]+p2[3][tid];
    catg[(size_t)b*1536 + d0 + tid]       = s1_*invnp[b];
    catg[(size_t)b*1536 + 768 + d0 + tid] = s2_*invnh[b];
  }
}

// K10: classifier head
__global__ __launch_bounds__(64) void k_cls(const float* __restrict__ comb,
    const float* __restrict__ w1, const float* __restrict__ b1,
    const float* __restrict__ w2, const float* __restrict__ b2, float* __restrict__ out){
  int b=blockIdx.x, tid=threadIdx.x;
  __shared__ float cb[512];
  __shared__ float t1[64];
  for (int i=tid;i<512;i+=64) cb[i]=comb[b*512+i];
  __syncthreads();
  float a = b1[tid];
  for (int k=0;k<512;k++) a += cb[k]*w1[(size_t)k*64+tid];
  t1[tid]=telu_f(a);
  __syncthreads();
  if (tid<3){
    float o = b2[tid];
    for (int k=0;k<64;k++) o += t1[k]*w2[k*3+tid];
    out[b*3+tid]=o;
  }
}

extern "C" void kernel_launch(void* const* d_in, const int* in_sizes, int n_in,
                              void* d_out, int out_size, void* d_ws, size_t ws_size,
                              hipStream_t stream){
  const float* hs   = (const float*)d_in[0];
  const int*   ids  = (const int*)d_in[1];
  const int*   amask= (const int*)d_in[2];
  const float* fe_w1= (const float*)d_in[3];
  const float* fe_b1= (const float*)d_in[4];
  const float* fe_g = (const float*)d_in[5];
  const float* fe_be= (const float*)d_in[6];
  const float* fe_w2= (const float*)d_in[7];
  const float* fe_b2= (const float*)d_in[8];
  const float* al_w1= (const float*)d_in[9];
  const float* al_b1= (const float*)d_in[10];
  const float* al_w2= (const float*)d_in[11];
  const float* al_b2= (const float*)d_in[12];
  const float* wq   = (const float*)d_in[13];
  const float* bq   = (const float*)d_in[14];
  const float* wk   = (const float*)d_in[15];
  const float* bk   = (const float*)d_in[16];
  const float* wv   = (const float*)d_in[17];
  const float* bv   = (const float*)d_in[18];
  const float* wo   = (const float*)d_in[19];
  const float* bo   = (const float*)d_in[20];
  const float* dpw  = (const float*)d_in[21];
  const float* dpb  = (const float*)d_in[22];
  const float* apw  = (const float*)d_in[23];
  const float* apb  = (const float*)d_in[24];
  const float* clw1 = (const float*)d_in[25];
  const float* clb1 = (const float*)d_in[26];
  const float* clw2 = (const float*)d_in[27];
  const float* clb2 = (const float*)d_in[28];
  float* out = (float*)d_out;

  char* base = (char*)d_ws;
  size_t off = 0;
  auto alloc = [&](size_t bytes)->char*{ char* p = base + off; off += (bytes + 255) & ~(size_t)255; return p; };
  short* hsb  = (short*)alloc((size_t)32*SS*HH*2);
  short* hsl  = (short*)alloc((size_t)32*SS*HH*2);
  short* Wt   = (short*)alloc((size_t)3*HH*HH*2);
  short* qbh  = (short*)alloc((size_t)32*SS*HH*2);
  short* kbh  = (short*)alloc((size_t)32*256*HH*2);
  float* vb   = (float*)alloc((size_t)32*256*HH*4);
  float* simb = (float*)alloc((size_t)32*SS*SS*4);
  float* uacc = (float*)alloc((size_t)32*8*256*4);       // zeroed
  float* v1g  = (float*)alloc((size_t)32*SS*4);          // zeroed
  float* v2g  = (float*)alloc((size_t)32*SS*4);          // zeroed
  int*   s1a  = (int*)alloc(32*4);
  int*   s2a  = (int*)alloc(32*4);
  float* invnam=(float*)alloc(32*4);
  float* invnp =(float*)alloc(32*4);
  float* invnh =(float*)alloc(32*4);
  float* xfe  = (float*)alloc((size_t)32*HH*4);
  float* sdiff= (float*)alloc((size_t)32*HH*4);
  float* comb = (float*)alloc((size_t)32*512*4);
  float4* repp= (float4*)alloc((size_t)32*6*4*128*16);
  float* featd= (float*)alloc((size_t)32*512*4);
  float* catg = (float*)alloc((size_t)32*1536*4);
  float* tmpg = (float*)alloc((size_t)32*HH*4);
  float* cmg  = (float*)alloc((size_t)32*HH*4);
  float* accg = (float*)alloc((size_t)32*HH*4);

  hipMemsetAsync(uacc, 0, (size_t)(32*8*256 + 32*SS + 32*SS)*4, stream);

  k_scan<<<dim3(32), dim3(512), 0, stream>>>(ids, amask, s1a, s2a, invnam, invnp, invnh);
  k_prep1<<<dim3(32,6,4), dim3(256), 0, stream>>>(hs, amask, s1a, s2a, hsb, hsl, repp);
  k_prep2<<<dim3(32,6), dim3(128), 0, stream>>>(hs, repp, invnam, invnp, invnh, xfe, sdiff);
  k_wt<<<dim3(24,24,3), dim3(256), 0, stream>>>(wq, wk, wv, Wt);
  k_bgemv<HH,512><<<dim3(32,4), dim3(256), 0, stream>>>(xfe, fe_w1, fe_b1, featd);
  k_feat2<<<dim3(32), dim3(256), 0, stream>>>(featd, fe_g, fe_be, fe_w2, fe_b2, comb);
  k_tail128<<<dim3(32), dim3(256), 0, stream>>>(sdiff, dpw, dpb, comb, 128);
  k_qkv_mfma<<<dim3(1536), dim3(256), 0, stream>>>(hsb, Wt, bq, bk, bv, qbh, kbh, vb);
  k_attn_mfma<<<dim3(32,8,8), dim3(256), 0, stream>>>(qbh, kbh, s1a, s2a, uacc);
  k_ctx<<<dim3(32,6), dim3(256), 0, stream>>>(uacc, vb, s1a, invnh, cmg);
  k_bgemv<HH,HH><<<dim3(32,6), dim3(256), 0, stream>>>(cmg, wo, bo, accg);
  k_tail128<<<dim3(32), dim3(256), 0, stream>>>(accg, apw, apb, comb, 256);
  k_sim_mfma<<<dim3(4,4,32), dim3(256), 0, stream>>>(hsb, hsl, s2a, simb);
  k_simsm<<<dim3(32,8), dim3(256), 0, stream>>>(simb, s1a, s2a, v1g, v2g);
  k_alvec<<<dim3(32,12), dim3(256), 0, stream>>>(hs, v1g, v2g, invnp, invnh, catg);
  k_bgemv<1536,HH><<<dim3(32,6), dim3(256), 0, stream>>>(catg, al_w1, al_b1, tmpg);
  k_tail128<<<dim3(32), dim3(256), 0, stream>>>(tmpg, al_w2, al_b2, comb, 384);
  k_cls<<<dim3(32), dim3(64), 0, stream>>>(comb, clw1, clb1, clw2, clb2, out);
}